// Round 9
// baseline (368.854 us; speedup 1.0000x reference)
//
#include <hip/hip_runtime.h>
#include <hip/hip_bf16.h>

// RecoveryODENetwork: fused x_model + GRU-ODE scan + output head, single kernel.
// B=2048, T=256, I=64, XH=128, G=Hd=64, O=24.
// Transposed matmuls Dt = W * h^T with MFMA 16x16x32 bf16.
//   A-frag (weights, const): lane holds A[row=l&15][k=8*(l>>4)+e]
//   B-frag (activations):    lane holds B[k=8*(l>>4)+e][col=l&15]   (col = batch)
//   D:                       lane holds D[row=4*(l>>4)+j][col=l&15] (m89-verified)
// Structure (best known: 313 us): 128 blocks x 512 thr. Waves 0-3 critical
// (recurrence), waves 4-7 helper (x_model pipe, GI, head). 3 windows/step
// (provably minimal barrier count for the cross-wave row-split):
//   A: helper GI_t             | crit P0 (r,z)
//   B: helper head t-1 + hid   | crit P1 (u; ODE Euler)   [GI reads hoisted]
//   C: helper xg_{t+1}         | crit P2 (GRU gates; h_new)
// R7: k-frag accumulator split (MFMA chain 2->1), GI hoist, full-loop setprio.
// R8: perm-packed trunc splits, clamp-free tanh, fma-form updates.
// R9: head moved A->B (h_{t-1} stable in Hhi through A+B; balances windows
//     6/8/4 helper vs 8/4/12 crit), z-MFMAs issued in r-dep-latency shadow.
// Recurrent operands (h, r*h, h') in LDS as bf16 hi+lo splits (exactness).
// Lite barriers (lgkmcnt only) keep x-prefetch global loads in flight.

#define T_STEPS 256

typedef short bf16x8 __attribute__((ext_vector_type(8)));
typedef short short4v __attribute__((ext_vector_type(4)));
typedef float f32x4 __attribute__((ext_vector_type(4)));

#define MFMA(a, b, c) __builtin_amdgcn_mfma_f32_16x16x32_bf16((a), (b), (c), 0, 0, 0)

// LDS-only barrier: orders ds ops across the block WITHOUT draining vmcnt.
__device__ __forceinline__ void barrier_lds() {
  asm volatile("s_waitcnt lgkmcnt(0)\n\ts_barrier" ::: "memory");
}

__device__ __forceinline__ short f2bf(float f) {
  __hip_bfloat16 b = __float2bfloat16(f);
  return __builtin_bit_cast(short, b);
}

__device__ __forceinline__ f32x4 sigm4(f32x4 x) {
  f32x4 r;
#pragma unroll
  for (int j = 0; j < 4; ++j) {
    float e = __builtin_amdgcn_exp2f(-1.442695041f * x[j]);
    r[j] = __builtin_amdgcn_rcpf(1.f + e);
  }
  return r;
}
// tanh(x) = 1 - 2/(exp2(2x*log2e)+1); inf/0 saturate correctly -> no clamp.
__device__ __forceinline__ f32x4 tanh4(f32x4 x) {
  f32x4 r;
#pragma unroll
  for (int j = 0; j < 4; ++j) {
    float e = __builtin_amdgcn_exp2f(2.885390082f * x[j]);
    r[j] = 1.f - 2.f * __builtin_amdgcn_rcpf(1.f + e);
  }
  return r;
}
__device__ __forceinline__ short4v cvt4(f32x4 v) {
  short4v p;
#pragma unroll
  for (int j = 0; j < 4; ++j) p[j] = f2bf(v[j]);
  return p;
}
// hi = trunc(v), lo = trunc(v - hi). Combined error ~2^-17 rel.
// Packing via v_perm_b32: 4 and + 4 sub + 4 perm = 12 VALU ops.
__device__ __forceinline__ void split_store(char* phi, char* plo, f32x4 v) {
  unsigned u0 = __builtin_bit_cast(unsigned, v[0]);
  unsigned u1 = __builtin_bit_cast(unsigned, v[1]);
  unsigned u2 = __builtin_bit_cast(unsigned, v[2]);
  unsigned u3 = __builtin_bit_cast(unsigned, v[3]);
  float l0 = v[0] - __builtin_bit_cast(float, u0 & 0xFFFF0000u);
  float l1 = v[1] - __builtin_bit_cast(float, u1 & 0xFFFF0000u);
  float l2 = v[2] - __builtin_bit_cast(float, u2 & 0xFFFF0000u);
  float l3 = v[3] - __builtin_bit_cast(float, u3 & 0xFFFF0000u);
  uint2 hi, lo;
  hi.x = __builtin_amdgcn_perm(u1, u0, 0x07060302u);  // [bf(v0), bf(v1)]
  hi.y = __builtin_amdgcn_perm(u3, u2, 0x07060302u);
  lo.x = __builtin_amdgcn_perm(__builtin_bit_cast(unsigned, l1),
                               __builtin_bit_cast(unsigned, l0), 0x07060302u);
  lo.y = __builtin_amdgcn_perm(__builtin_bit_cast(unsigned, l3),
                               __builtin_bit_cast(unsigned, l2), 0x07060302u);
  *(uint2*)phi = hi;
  *(uint2*)plo = lo;
}
__device__ __forceinline__ bf16x8 wfrag(const float* __restrict__ W, int stride, int row, int c0) {
  const float* p = W + (size_t)row * stride + c0;
  float4 a = *(const float4*)p;
  float4 b = *(const float4*)(p + 4);
  bf16x8 r;
  r[0] = f2bf(a.x); r[1] = f2bf(a.y); r[2] = f2bf(a.z); r[3] = f2bf(a.w);
  r[4] = f2bf(b.x); r[5] = f2bf(b.y); r[6] = f2bf(b.z); r[7] = f2bf(b.w);
  return r;
}

// XOR swizzle (G4): kills 16-way bank conflict of stride-128B/256B column reads
__device__ __forceinline__ int swz64(int row, int off) { return row * 128 + (off ^ ((row & 7) << 4)); }
__device__ __forceinline__ int swzH(int row, int off)  { return row * 256 + (off ^ ((row & 7) << 4)); }

__global__ __launch_bounds__(512, 1) void odegru(
    const float* __restrict__ H,
    const float* __restrict__ W1, const float* __restrict__ b1,
    const float* __restrict__ W2, const float* __restrict__ b2,
    const float* __restrict__ Wor, const float* __restrict__ Woz, const float* __restrict__ Woh,
    const float* __restrict__ wih, const float* __restrict__ whhg,
    const float* __restrict__ bih, const float* __restrict__ bhh,
    const float* __restrict__ Wr, const float* __restrict__ br,
    float* __restrict__ out) {
  const int tid = threadIdx.x;
  const int w = tid >> 6;          // wave 0..7
  const int l = tid & 63;
  const int col = l & 15;          // batch column within tile
  const int g = l >> 4;            // lane group
  const int b0 = blockIdx.x << 4;
  const bool helper = (w >= 4);
  const int hw = w - 4;            // helper wave index 0..3
  const f32x4 zero4 = {0.f, 0.f, 0.f, 0.f};

  __shared__ __align__(16) char sm[30720];
  char* HIDb = sm;            // [16 cols][256B] bf16 hid (x_model stage1), swizzled
  char* XGb  = sm + 4096;     // [16 cols][128B] bf16 xg, swizzled
  char* Hhi  = sm + 6144;     // h state hi
  char* Hlo  = sm + 8192;     // h state lo
  char* RHhi = sm + 10240;    // r*h hi
  char* RHlo = sm + 12288;    // r*h lo
  char* H2hi = sm + 14336;    // h' hi
  char* H2lo = sm + 16384;    // h' lo
  char* GIb  = sm + 18432;    // [gate3][wave4][lane64] float4 = 12288B

  // zero h state (hi+lo): 4096B, 512 threads x 8B
  ((long long*)Hhi)[tid] = 0;

  // ---- common LDS offsets ----
  const int row4 = 16 * (helper ? hw : w) + 4 * g;  // D-row base of this wave's tile
  const int r16 = 16 * (helper ? hw : w) + col;     // A-frag row base
  const int sR0 = swz64(col, 16 * g);
  const int sR1 = swz64(col, 64 + 16 * g);
  const int sW  = swz64(col, row4 * 2);

  // =======================================================================
  // per-role setup
  // =======================================================================
  bf16x8 aR0, aR1, aZ0, aZ1, aU0, aU1, aHR0, aHR1, aHZ0, aHZ1, aHN0, aHN1;
  f32x4 bhn;
  bf16x8 aW1_00, aW1_01, aW1_10, aW1_11, aW2_0, aW2_1, aW2_2, aW2_3;
  bf16x8 aIR0, aIR1, aIZ0, aIZ1, aIN0, aIN1, aWr0, aWr1;
  f32x4 bsr, bsz, bin_, b1a, b1b, b2w, brw;
  const float* xp = nullptr;
  float4 xa, xb, xc, xd;
  float* outp = nullptr;
  int sHid0, sHid1, sHid2, sHid3, sHidW0, sHidW1, giW;
  const int giR = (w * 64 + l) * 16;  // identity mapping to helper hw==w, same lane

  if (!helper) {
    aR0 = wfrag(Wor, 64, r16, 8 * g);          aR1 = wfrag(Wor, 64, r16, 32 + 8 * g);
    aZ0 = wfrag(Woz, 64, r16, 8 * g);          aZ1 = wfrag(Woz, 64, r16, 32 + 8 * g);
    aU0 = wfrag(Woh, 64, r16, 8 * g);          aU1 = wfrag(Woh, 64, r16, 32 + 8 * g);
    aHR0 = wfrag(whhg, 64, r16, 8 * g);        aHR1 = wfrag(whhg, 64, r16, 32 + 8 * g);
    aHZ0 = wfrag(whhg, 64, 64 + r16, 8 * g);   aHZ1 = wfrag(whhg, 64, 64 + r16, 32 + 8 * g);
    aHN0 = wfrag(whhg, 64, 128 + r16, 8 * g);  aHN1 = wfrag(whhg, 64, 128 + r16, 32 + 8 * g);
#pragma unroll
    for (int j = 0; j < 4; ++j) bhn[j] = bhh[128 + row4 + j];
  } else {
    aW1_00 = wfrag(W1, 64, r16, 8 * g);        aW1_01 = wfrag(W1, 64, r16, 32 + 8 * g);
    aW1_10 = wfrag(W1, 64, 64 + r16, 8 * g);   aW1_11 = wfrag(W1, 64, 64 + r16, 32 + 8 * g);
    aW2_0 = wfrag(W2, 128, r16, 8 * g);        aW2_1 = wfrag(W2, 128, r16, 32 + 8 * g);
    aW2_2 = wfrag(W2, 128, r16, 64 + 8 * g);   aW2_3 = wfrag(W2, 128, r16, 96 + 8 * g);
    aIR0 = wfrag(wih, 64, r16, 8 * g);         aIR1 = wfrag(wih, 64, r16, 32 + 8 * g);
    aIZ0 = wfrag(wih, 64, 64 + r16, 8 * g);    aIZ1 = wfrag(wih, 64, 64 + r16, 32 + 8 * g);
    aIN0 = wfrag(wih, 64, 128 + r16, 8 * g);   aIN1 = wfrag(wih, 64, 128 + r16, 32 + 8 * g);
    const int wr_row = r16 > 23 ? 23 : r16;    // Wr has 24 rows; clamp (unused rows)
    aWr0 = wfrag(Wr, 64, wr_row, 8 * g);       aWr1 = wfrag(Wr, 64, wr_row, 32 + 8 * g);
#pragma unroll
    for (int j = 0; j < 4; ++j) {
      bsr[j] = bih[row4 + j] + bhh[row4 + j];
      bsz[j] = bih[64 + row4 + j] + bhh[64 + row4 + j];
      bin_[j] = bih[128 + row4 + j];
      b1a[j] = b1[row4 + j];
      b1b[j] = b1[64 + row4 + j];
      b2w[j] = b2[row4 + j];
      int o = row4 + j;
      brw[j] = br[o > 23 ? 23 : o];
    }
    sHid0 = swzH(col, 16 * g);
    sHid1 = swzH(col, 64 + 16 * g);
    sHid2 = swzH(col, 128 + 16 * g);
    sHid3 = swzH(col, 192 + 16 * g);
    sHidW0 = swzH(col, row4 * 2);
    sHidW1 = swzH(col, (64 + row4) * 2);
    giW = (hw * 64 + l) * 16;
    xp = H + ((size_t)(b0 + col) * T_STEPS) * 64 + 8 * g;
    xa = *(const float4*)(xp);      xb = *(const float4*)(xp + 4);
    xc = *(const float4*)(xp + 32); xd = *(const float4*)(xp + 36);
    outp = out + ((size_t)(b0 + col) * T_STEPS) * 24 + row4;
  }

  f32x4 hreg = {0.f, 0.f, 0.f, 0.f};  // critical: h^T[row4+j][col] in fp32

  // =======================================================================
  // prologue: helpers compute hid_0, xg_0 so GI_0 is ready in loop iter 0
  // =======================================================================
  if (helper) {
    bf16x8 xB0, xB1;
    xB0[0] = f2bf(xa.x); xB0[1] = f2bf(xa.y); xB0[2] = f2bf(xa.z); xB0[3] = f2bf(xa.w);
    xB0[4] = f2bf(xb.x); xB0[5] = f2bf(xb.y); xB0[6] = f2bf(xb.z); xB0[7] = f2bf(xb.w);
    xB1[0] = f2bf(xc.x); xB1[1] = f2bf(xc.y); xB1[2] = f2bf(xc.z); xB1[3] = f2bf(xc.w);
    xB1[4] = f2bf(xd.x); xB1[5] = f2bf(xd.y); xB1[6] = f2bf(xd.z); xB1[7] = f2bf(xd.w);
    f32x4 hid0 = MFMA(aW1_00, xB0, b1a), hid0b = MFMA(aW1_01, xB1, zero4);
    f32x4 hid1 = MFMA(aW1_10, xB0, b1b), hid1b = MFMA(aW1_11, xB1, zero4);
    hid0 += hid0b; hid1 += hid1b;
#pragma unroll
    for (int j = 0; j < 4; ++j) { hid0[j] = fmaxf(hid0[j], 0.f); hid1[j] = fmaxf(hid1[j], 0.f); }
    *(short4v*)(HIDb + sHidW0) = cvt4(hid0);
    *(short4v*)(HIDb + sHidW1) = cvt4(hid1);
  }
  barrier_lds();
  if (helper) {
    bf16x8 hdB0 = *(const bf16x8*)(HIDb + sHid0);
    bf16x8 hdB1 = *(const bf16x8*)(HIDb + sHid1);
    bf16x8 hdB2 = *(const bf16x8*)(HIDb + sHid2);
    bf16x8 hdB3 = *(const bf16x8*)(HIDb + sHid3);
    f32x4 x0 = MFMA(aW2_0, hdB0, b2w),  x1 = MFMA(aW2_1, hdB1, zero4);
    f32x4 x2 = MFMA(aW2_2, hdB2, zero4), x3 = MFMA(aW2_3, hdB3, zero4);
    *(short4v*)(XGb + sW) = cvt4((x0 + x1) + (x2 + x3));
    // advance prefetch: regs <- x_1 (consumed in window B of iter 0)
    xp += 64;
    xa = *(const float4*)(xp);      xb = *(const float4*)(xp + 4);
    xc = *(const float4*)(xp + 32); xd = *(const float4*)(xp + 36);
  }
  barrier_lds();

  // =======================================================================
  // main scan
  // =======================================================================
  for (int t = 0; t < T_STEPS; ++t) {
    if (helper) {
      // ============== window A: GI_t ==============
      bf16x8 xgB0 = *(const bf16x8*)(XGb + sR0);
      bf16x8 xgB1 = *(const bf16x8*)(XGb + sR1);
      f32x4 gr0 = MFMA(aIR0, xgB0, bsr),  gr1 = MFMA(aIR1, xgB1, zero4);
      f32x4 gz0 = MFMA(aIZ0, xgB0, bsz),  gz1 = MFMA(aIZ1, xgB1, zero4);
      f32x4 gn0 = MFMA(aIN0, xgB0, bin_), gn1 = MFMA(aIN1, xgB1, zero4);
      *(f32x4*)(GIb + 0 * 4096 + giW) = gr0 + gr1;
      *(f32x4*)(GIb + 1 * 4096 + giW) = gz0 + gz1;
      *(f32x4*)(GIb + 2 * 4096 + giW) = gn0 + gn1;
      barrier_lds();
      // ============== window B: head t-1 + hid_{t+1} ==============
      // h_{t-1} is stable in Hhi/Hlo through windows A and B (P2 rewrites it).
      if (hw < 2 && t > 0) {
        bf16x8 hB0h = *(const bf16x8*)(Hhi + sR0);
        bf16x8 hB1h = *(const bf16x8*)(Hhi + sR1);
        bf16x8 hB0l = *(const bf16x8*)(Hlo + sR0);
        bf16x8 hB1l = *(const bf16x8*)(Hlo + sR1);
        f32x4 a5 = MFMA(aWr0, hB0h, brw),   a5b = MFMA(aWr1, hB1h, zero4);
        f32x4 a5l = MFMA(aWr0, hB0l, zero4), a5lb = MFMA(aWr1, hB1l, zero4);
        a5 = (a5 + a5b) + (a5l + a5lb);
        if (hw == 0 || g < 2) { outp[0] = a5[0]; outp[1] = a5[1]; outp[2] = a5[2]; outp[3] = a5[3]; }
        outp += 24;
      }
      if (t + 1 < T_STEPS) {
        bf16x8 xB0, xB1;
        xB0[0] = f2bf(xa.x); xB0[1] = f2bf(xa.y); xB0[2] = f2bf(xa.z); xB0[3] = f2bf(xa.w);
        xB0[4] = f2bf(xb.x); xB0[5] = f2bf(xb.y); xB0[6] = f2bf(xb.z); xB0[7] = f2bf(xb.w);
        xB1[0] = f2bf(xc.x); xB1[1] = f2bf(xc.y); xB1[2] = f2bf(xc.z); xB1[3] = f2bf(xc.w);
        xB1[4] = f2bf(xd.x); xB1[5] = f2bf(xd.y); xB1[6] = f2bf(xd.z); xB1[7] = f2bf(xd.w);
        if (t + 2 < T_STEPS) {  // prefetch x_{t+2}; stays in flight across lite barriers
          xp += 64;
          xa = *(const float4*)(xp);      xb = *(const float4*)(xp + 4);
          xc = *(const float4*)(xp + 32); xd = *(const float4*)(xp + 36);
        }
        f32x4 hid0 = MFMA(aW1_00, xB0, b1a), hid0b = MFMA(aW1_01, xB1, zero4);
        f32x4 hid1 = MFMA(aW1_10, xB0, b1b), hid1b = MFMA(aW1_11, xB1, zero4);
        hid0 += hid0b; hid1 += hid1b;
#pragma unroll
        for (int j = 0; j < 4; ++j) { hid0[j] = fmaxf(hid0[j], 0.f); hid1[j] = fmaxf(hid1[j], 0.f); }
        *(short4v*)(HIDb + sHidW0) = cvt4(hid0);
        *(short4v*)(HIDb + sHidW1) = cvt4(hid1);
      }
      barrier_lds();
      // ============== window C: xg_{t+1} ==============
      if (t + 1 < T_STEPS) {
        bf16x8 hdB0 = *(const bf16x8*)(HIDb + sHid0);
        bf16x8 hdB1 = *(const bf16x8*)(HIDb + sHid1);
        bf16x8 hdB2 = *(const bf16x8*)(HIDb + sHid2);
        bf16x8 hdB3 = *(const bf16x8*)(HIDb + sHid3);
        f32x4 x0 = MFMA(aW2_0, hdB0, b2w),   x1 = MFMA(aW2_1, hdB1, zero4);
        f32x4 x2 = MFMA(aW2_2, hdB2, zero4), x3 = MFMA(aW2_3, hdB3, zero4);
        *(short4v*)(XGb + sW) = cvt4((x0 + x1) + (x2 + x3));
      }
      barrier_lds();
    } else {
      __builtin_amdgcn_s_setprio(1);
      // ============== P0 (window A): r,z from h ==============
      bf16x8 hB0h = *(const bf16x8*)(Hhi + sR0);
      bf16x8 hB1h = *(const bf16x8*)(Hhi + sR1);
      bf16x8 hB0l = *(const bf16x8*)(Hlo + sR0);
      bf16x8 hB1l = *(const bf16x8*)(Hlo + sR1);
      // k-frag split: independent MFMAs; z issued in r's dep-latency shadow
      f32x4 r00 = MFMA(aR0, hB0h, zero4), r10 = MFMA(aR1, hB1h, zero4);
      f32x4 r01 = MFMA(aR0, hB0l, zero4), r11 = MFMA(aR1, hB1l, zero4);
      f32x4 z00 = MFMA(aZ0, hB0h, zero4), z10 = MFMA(aZ1, hB1h, zero4);
      f32x4 z01 = MFMA(aZ0, hB0l, zero4), z11 = MFMA(aZ1, hB1l, zero4);
      f32x4 rr = sigm4((r00 + r10) + (r01 + r11));
      split_store(RHhi + sW, RHlo + sW, rr * hreg);
      f32x4 zz = sigm4((z00 + z10) + (z01 + z11));  // overlaps barrier wait
      barrier_lds();
      // ============== P1 (window B): u; ODE Euler; GI preload ==============
      bf16x8 rhB0h = *(const bf16x8*)(RHhi + sR0);
      bf16x8 rhB1h = *(const bf16x8*)(RHhi + sR1);
      bf16x8 rhB0l = *(const bf16x8*)(RHlo + sR0);
      bf16x8 rhB1l = *(const bf16x8*)(RHlo + sR1);
      // GI_t stable since end of window A: hoist reads here (consumed in C)
      f32x4 gir = *(const f32x4*)(GIb + 0 * 4096 + giR);
      f32x4 giz = *(const f32x4*)(GIb + 1 * 4096 + giR);
      f32x4 gin = *(const f32x4*)(GIb + 2 * 4096 + giR);
      f32x4 u00 = MFMA(aU0, rhB0h, zero4), u10 = MFMA(aU1, rhB1h, zero4);
      f32x4 u01 = MFMA(aU0, rhB0l, zero4), u11 = MFMA(aU1, rhB1l, zero4);
      f32x4 uu = tanh4((u00 + u10) + (u01 + u11));
      f32x4 hp = uu - zz * (uu - hreg);  // ODE Euler (DT=1): h + (1-z)(u-h)
      split_store(H2hi + sW, H2lo + sW, hp);
      barrier_lds();
      // ============== P2 (window C): GRU gates; h_new ==============
      bf16x8 h2B0h = *(const bf16x8*)(H2hi + sR0);
      bf16x8 h2B1h = *(const bf16x8*)(H2hi + sR1);
      bf16x8 h2B0l = *(const bf16x8*)(H2lo + sR0);
      bf16x8 h2B1l = *(const bf16x8*)(H2lo + sR1);
      // issue order = consumption order: hr (r2), hn (nn), hz (z2)
      f32x4 hr00 = MFMA(aHR0, h2B0h, zero4), hr10 = MFMA(aHR1, h2B1h, zero4);
      f32x4 hr01 = MFMA(aHR0, h2B0l, zero4), hr11 = MFMA(aHR1, h2B1l, zero4);
      f32x4 hn00 = MFMA(aHN0, h2B0h, bhn),   hn10 = MFMA(aHN1, h2B1h, zero4);
      f32x4 hn01 = MFMA(aHN0, h2B0l, zero4), hn11 = MFMA(aHN1, h2B1l, zero4);
      f32x4 hz00 = MFMA(aHZ0, h2B0h, zero4), hz10 = MFMA(aHZ1, h2B1h, zero4);
      f32x4 hz01 = MFMA(aHZ0, h2B0l, zero4), hz11 = MFMA(aHZ1, h2B1l, zero4);
      f32x4 r2 = sigm4(gir + (hr00 + hr10) + (hr01 + hr11));
      f32x4 nn = tanh4(gin + r2 * ((hn00 + hn10) + (hn01 + hn11)));
      f32x4 z2 = sigm4(giz + (hz00 + hz10) + (hz01 + hz11));
      hreg = nn + z2 * (hp - nn);  // h_new = (1-z2)*nn + z2*hp
      split_store(Hhi + sW, Hlo + sW, hreg);
      __builtin_amdgcn_s_setprio(0);
      barrier_lds();
    }
  }

  // epilogue: output head for t = T-1 (Hhi/Hlo hold h_{T-1})
  if (helper && hw < 2) {
    bf16x8 hB0h = *(const bf16x8*)(Hhi + sR0);
    bf16x8 hB1h = *(const bf16x8*)(Hhi + sR1);
    bf16x8 hB0l = *(const bf16x8*)(Hlo + sR0);
    bf16x8 hB1l = *(const bf16x8*)(Hlo + sR1);
    f32x4 a5 = MFMA(aWr0, hB0h, brw),   a5b = MFMA(aWr1, hB1h, zero4);
    f32x4 a5l = MFMA(aWr0, hB0l, zero4), a5lb = MFMA(aWr1, hB1l, zero4);
    a5 = (a5 + a5b) + (a5l + a5lb);
    if (hw == 0 || g < 2) { outp[0] = a5[0]; outp[1] = a5[1]; outp[2] = a5[2]; outp[3] = a5[3]; }
  }
}

extern "C" void kernel_launch(void* const* d_in, const int* in_sizes, int n_in,
                              void* d_out, int out_size, void* d_ws, size_t ws_size,
                              hipStream_t stream) {
  (void)in_sizes; (void)n_in; (void)d_ws; (void)ws_size; (void)out_size;
  const float* H   = (const float*)d_in[0];
  // d_in[1] = times (unused: delta_t == 1 -> exactly one Euler step per observation)
  const float* W1  = (const float*)d_in[2];
  const float* b1  = (const float*)d_in[3];
  const float* W2  = (const float*)d_in[4];
  const float* b2  = (const float*)d_in[5];
  const float* Whr = (const float*)d_in[6];
  const float* Whz = (const float*)d_in[7];
  const float* Whh = (const float*)d_in[8];
  const float* wih = (const float*)d_in[9];
  const float* whh = (const float*)d_in[10];
  const float* bih = (const float*)d_in[11];
  const float* bhh = (const float*)d_in[12];
  const float* Wr  = (const float*)d_in[13];
  const float* br  = (const float*)d_in[14];
  float* out = (float*)d_out;

  odegru<<<dim3(2048 / 16), dim3(512), 0, stream>>>(
      H, W1, b1, W2, b2, Whr, Whz, Whh, wih, whh, bih, bhh, Wr, br, out);
}

// Round 10
// 333.939 us; speedup vs baseline: 1.1046x; 1.1046x over previous
//
#include <hip/hip_runtime.h>
#include <hip/hip_bf16.h>

// RecoveryODENetwork: fused x_model + GRU-ODE scan + output head, single kernel.
// B=2048, T=256, I=64, XH=128, G=Hd=64, O=24.
// Transposed matmuls Dt = W * h^T with MFMA 16x16x32 bf16.
//   A-frag (weights, const): lane holds A[row=l&15][k=8*(l>>4)+e]
//   B-frag (activations):    lane holds B[k=8*(l>>4)+e][col=l&15]   (col = batch)
//   D:                       lane holds D[row=4*(l>>4)+j][col=l&15] (m89-verified)
// Structure (R8 = best known 313 us): 128 blocks x 512 thr. Waves 0-3 critical
// (recurrence), waves 4-7 helper. 3 windows/step (minimal barrier count):
//   A: helper GI_t            | crit P0 (r,z)
//   B: helper hid_{t+1}       | crit P1 (u; ODE Euler)   [GI reads hoisted]
//   C: helper xg_{t+1}+head   | crit P2 (GRU gates; h_new)
// R7: k-frag accumulator split (MFMA chain 2->1), GI hoist, full-loop setprio.
// R8: perm-packed trunc splits, clamp-free tanh, fma-form updates.
// R10 (single isolated change vs R8): head moved window A -> C, made legal by
//   DOUBLE-BUFFERING the h state (write buf[t&1], read buf[(t-1)&1]): helper
//   reads h_{t-1} in C while crit writes h_t to the other buffer. Balances
//   windows A: 8v6 (was 8v10), C: 12v8 (was 12v4).
// Recurrent operands (h, r*h, h') in LDS as bf16 hi+lo splits (exactness).
// Lite barriers (lgkmcnt only) keep x-prefetch global loads in flight.

#define T_STEPS 256

typedef short bf16x8 __attribute__((ext_vector_type(8)));
typedef short short4v __attribute__((ext_vector_type(4)));
typedef float f32x4 __attribute__((ext_vector_type(4)));

#define MFMA(a, b, c) __builtin_amdgcn_mfma_f32_16x16x32_bf16((a), (b), (c), 0, 0, 0)

// LDS-only barrier: orders ds ops across the block WITHOUT draining vmcnt.
__device__ __forceinline__ void barrier_lds() {
  asm volatile("s_waitcnt lgkmcnt(0)\n\ts_barrier" ::: "memory");
}

__device__ __forceinline__ short f2bf(float f) {
  __hip_bfloat16 b = __float2bfloat16(f);
  return __builtin_bit_cast(short, b);
}

__device__ __forceinline__ f32x4 sigm4(f32x4 x) {
  f32x4 r;
#pragma unroll
  for (int j = 0; j < 4; ++j) {
    float e = __builtin_amdgcn_exp2f(-1.442695041f * x[j]);
    r[j] = __builtin_amdgcn_rcpf(1.f + e);
  }
  return r;
}
// tanh(x) = 1 - 2/(exp2(2x*log2e)+1); inf/0 saturate correctly -> no clamp.
__device__ __forceinline__ f32x4 tanh4(f32x4 x) {
  f32x4 r;
#pragma unroll
  for (int j = 0; j < 4; ++j) {
    float e = __builtin_amdgcn_exp2f(2.885390082f * x[j]);
    r[j] = 1.f - 2.f * __builtin_amdgcn_rcpf(1.f + e);
  }
  return r;
}
__device__ __forceinline__ short4v cvt4(f32x4 v) {
  short4v p;
#pragma unroll
  for (int j = 0; j < 4; ++j) p[j] = f2bf(v[j]);
  return p;
}
// hi = trunc(v), lo = trunc(v - hi). Combined error ~2^-17 rel.
// Packing via v_perm_b32: 4 and + 4 sub + 4 perm = 12 VALU ops.
__device__ __forceinline__ void split_store(char* phi, char* plo, f32x4 v) {
  unsigned u0 = __builtin_bit_cast(unsigned, v[0]);
  unsigned u1 = __builtin_bit_cast(unsigned, v[1]);
  unsigned u2 = __builtin_bit_cast(unsigned, v[2]);
  unsigned u3 = __builtin_bit_cast(unsigned, v[3]);
  float l0 = v[0] - __builtin_bit_cast(float, u0 & 0xFFFF0000u);
  float l1 = v[1] - __builtin_bit_cast(float, u1 & 0xFFFF0000u);
  float l2 = v[2] - __builtin_bit_cast(float, u2 & 0xFFFF0000u);
  float l3 = v[3] - __builtin_bit_cast(float, u3 & 0xFFFF0000u);
  uint2 hi, lo;
  hi.x = __builtin_amdgcn_perm(u1, u0, 0x07060302u);  // [bf(v0), bf(v1)]
  hi.y = __builtin_amdgcn_perm(u3, u2, 0x07060302u);
  lo.x = __builtin_amdgcn_perm(__builtin_bit_cast(unsigned, l1),
                               __builtin_bit_cast(unsigned, l0), 0x07060302u);
  lo.y = __builtin_amdgcn_perm(__builtin_bit_cast(unsigned, l3),
                               __builtin_bit_cast(unsigned, l2), 0x07060302u);
  *(uint2*)phi = hi;
  *(uint2*)plo = lo;
}
__device__ __forceinline__ bf16x8 wfrag(const float* __restrict__ W, int stride, int row, int c0) {
  const float* p = W + (size_t)row * stride + c0;
  float4 a = *(const float4*)p;
  float4 b = *(const float4*)(p + 4);
  bf16x8 r;
  r[0] = f2bf(a.x); r[1] = f2bf(a.y); r[2] = f2bf(a.z); r[3] = f2bf(a.w);
  r[4] = f2bf(b.x); r[5] = f2bf(b.y); r[6] = f2bf(b.z); r[7] = f2bf(b.w);
  return r;
}

// XOR swizzle (G4): kills 16-way bank conflict of stride-128B/256B column reads
__device__ __forceinline__ int swz64(int row, int off) { return row * 128 + (off ^ ((row & 7) << 4)); }
__device__ __forceinline__ int swzH(int row, int off)  { return row * 256 + (off ^ ((row & 7) << 4)); }

__global__ __launch_bounds__(512, 1) void odegru(
    const float* __restrict__ H,
    const float* __restrict__ W1, const float* __restrict__ b1,
    const float* __restrict__ W2, const float* __restrict__ b2,
    const float* __restrict__ Wor, const float* __restrict__ Woz, const float* __restrict__ Woh,
    const float* __restrict__ wih, const float* __restrict__ whhg,
    const float* __restrict__ bih, const float* __restrict__ bhh,
    const float* __restrict__ Wr, const float* __restrict__ br,
    float* __restrict__ out) {
  const int tid = threadIdx.x;
  const int w = tid >> 6;          // wave 0..7
  const int l = tid & 63;
  const int col = l & 15;          // batch column within tile
  const int g = l >> 4;            // lane group
  const int b0 = blockIdx.x << 4;
  const bool helper = (w >= 4);
  const int hw = w - 4;            // helper wave index 0..3
  const f32x4 zero4 = {0.f, 0.f, 0.f, 0.f};

  __shared__ __align__(16) char sm[34816];
  char* HIDb = sm;            // [16 cols][256B] bf16 hid (x_model stage1), swizzled
  char* XGb  = sm + 4096;     // [16 cols][128B] bf16 xg, swizzled
  char* Hhi0 = sm + 6144;     // h state hi, buffer 0
  char* Hlo0 = sm + 8192;     // h state lo, buffer 0
  char* RHhi = sm + 10240;    // r*h hi
  char* RHlo = sm + 12288;    // r*h lo
  char* H2hi = sm + 14336;    // h' hi
  char* H2lo = sm + 16384;    // h' lo
  char* GIb  = sm + 18432;    // [gate3][wave4][lane64] float4 = 12288B
  char* Hhi1 = sm + 30720;    // h state hi, buffer 1
  char* Hlo1 = sm + 32768;    // h state lo, buffer 1

  // zero both h buffers (hi+lo): 2 x 4096B, 512 threads x 8B each
  ((long long*)Hhi0)[tid] = 0;
  ((long long*)Hhi1)[tid] = 0;

  // double-buffer pointers: write buf[t&1], read buf[(t-1)&1]; h_0=0 in buf1
  char* HhiR = Hhi1; char* HloR = Hlo1;
  char* HhiW = Hhi0; char* HloW = Hlo0;

  // ---- common LDS offsets ----
  const int row4 = 16 * (helper ? hw : w) + 4 * g;  // D-row base of this wave's tile
  const int r16 = 16 * (helper ? hw : w) + col;     // A-frag row base
  const int sR0 = swz64(col, 16 * g);
  const int sR1 = swz64(col, 64 + 16 * g);
  const int sW  = swz64(col, row4 * 2);

  // =======================================================================
  // per-role setup
  // =======================================================================
  bf16x8 aR0, aR1, aZ0, aZ1, aU0, aU1, aHR0, aHR1, aHZ0, aHZ1, aHN0, aHN1;
  f32x4 bhn;
  bf16x8 aW1_00, aW1_01, aW1_10, aW1_11, aW2_0, aW2_1, aW2_2, aW2_3;
  bf16x8 aIR0, aIR1, aIZ0, aIZ1, aIN0, aIN1, aWr0, aWr1;
  f32x4 bsr, bsz, bin_, b1a, b1b, b2w, brw;
  const float* xp = nullptr;
  float4 xa, xb, xc, xd;
  float* outp = nullptr;
  int sHid0, sHid1, sHid2, sHid3, sHidW0, sHidW1, giW;
  const int giR = (w * 64 + l) * 16;  // identity mapping to helper hw==w, same lane

  if (!helper) {
    aR0 = wfrag(Wor, 64, r16, 8 * g);          aR1 = wfrag(Wor, 64, r16, 32 + 8 * g);
    aZ0 = wfrag(Woz, 64, r16, 8 * g);          aZ1 = wfrag(Woz, 64, r16, 32 + 8 * g);
    aU0 = wfrag(Woh, 64, r16, 8 * g);          aU1 = wfrag(Woh, 64, r16, 32 + 8 * g);
    aHR0 = wfrag(whhg, 64, r16, 8 * g);        aHR1 = wfrag(whhg, 64, r16, 32 + 8 * g);
    aHZ0 = wfrag(whhg, 64, 64 + r16, 8 * g);   aHZ1 = wfrag(whhg, 64, 64 + r16, 32 + 8 * g);
    aHN0 = wfrag(whhg, 64, 128 + r16, 8 * g);  aHN1 = wfrag(whhg, 64, 128 + r16, 32 + 8 * g);
#pragma unroll
    for (int j = 0; j < 4; ++j) bhn[j] = bhh[128 + row4 + j];
  } else {
    aW1_00 = wfrag(W1, 64, r16, 8 * g);        aW1_01 = wfrag(W1, 64, r16, 32 + 8 * g);
    aW1_10 = wfrag(W1, 64, 64 + r16, 8 * g);   aW1_11 = wfrag(W1, 64, 64 + r16, 32 + 8 * g);
    aW2_0 = wfrag(W2, 128, r16, 8 * g);        aW2_1 = wfrag(W2, 128, r16, 32 + 8 * g);
    aW2_2 = wfrag(W2, 128, r16, 64 + 8 * g);   aW2_3 = wfrag(W2, 128, r16, 96 + 8 * g);
    aIR0 = wfrag(wih, 64, r16, 8 * g);         aIR1 = wfrag(wih, 64, r16, 32 + 8 * g);
    aIZ0 = wfrag(wih, 64, 64 + r16, 8 * g);    aIZ1 = wfrag(wih, 64, 64 + r16, 32 + 8 * g);
    aIN0 = wfrag(wih, 64, 128 + r16, 8 * g);   aIN1 = wfrag(wih, 64, 128 + r16, 32 + 8 * g);
    const int wr_row = r16 > 23 ? 23 : r16;    // Wr has 24 rows; clamp (unused rows)
    aWr0 = wfrag(Wr, 64, wr_row, 8 * g);       aWr1 = wfrag(Wr, 64, wr_row, 32 + 8 * g);
#pragma unroll
    for (int j = 0; j < 4; ++j) {
      bsr[j] = bih[row4 + j] + bhh[row4 + j];
      bsz[j] = bih[64 + row4 + j] + bhh[64 + row4 + j];
      bin_[j] = bih[128 + row4 + j];
      b1a[j] = b1[row4 + j];
      b1b[j] = b1[64 + row4 + j];
      b2w[j] = b2[row4 + j];
      int o = row4 + j;
      brw[j] = br[o > 23 ? 23 : o];
    }
    sHid0 = swzH(col, 16 * g);
    sHid1 = swzH(col, 64 + 16 * g);
    sHid2 = swzH(col, 128 + 16 * g);
    sHid3 = swzH(col, 192 + 16 * g);
    sHidW0 = swzH(col, row4 * 2);
    sHidW1 = swzH(col, (64 + row4) * 2);
    giW = (hw * 64 + l) * 16;
    xp = H + ((size_t)(b0 + col) * T_STEPS) * 64 + 8 * g;
    xa = *(const float4*)(xp);      xb = *(const float4*)(xp + 4);
    xc = *(const float4*)(xp + 32); xd = *(const float4*)(xp + 36);
    outp = out + ((size_t)(b0 + col) * T_STEPS) * 24 + row4;
  }

  f32x4 hreg = {0.f, 0.f, 0.f, 0.f};  // critical: h^T[row4+j][col] in fp32

  // =======================================================================
  // prologue: helpers compute hid_0, xg_0 so GI_0 is ready in loop iter 0
  // =======================================================================
  if (helper) {
    bf16x8 xB0, xB1;
    xB0[0] = f2bf(xa.x); xB0[1] = f2bf(xa.y); xB0[2] = f2bf(xa.z); xB0[3] = f2bf(xa.w);
    xB0[4] = f2bf(xb.x); xB0[5] = f2bf(xb.y); xB0[6] = f2bf(xb.z); xB0[7] = f2bf(xb.w);
    xB1[0] = f2bf(xc.x); xB1[1] = f2bf(xc.y); xB1[2] = f2bf(xc.z); xB1[3] = f2bf(xc.w);
    xB1[4] = f2bf(xd.x); xB1[5] = f2bf(xd.y); xB1[6] = f2bf(xd.z); xB1[7] = f2bf(xd.w);
    f32x4 hid0 = MFMA(aW1_00, xB0, b1a), hid0b = MFMA(aW1_01, xB1, zero4);
    f32x4 hid1 = MFMA(aW1_10, xB0, b1b), hid1b = MFMA(aW1_11, xB1, zero4);
    hid0 += hid0b; hid1 += hid1b;
#pragma unroll
    for (int j = 0; j < 4; ++j) { hid0[j] = fmaxf(hid0[j], 0.f); hid1[j] = fmaxf(hid1[j], 0.f); }
    *(short4v*)(HIDb + sHidW0) = cvt4(hid0);
    *(short4v*)(HIDb + sHidW1) = cvt4(hid1);
  }
  barrier_lds();
  if (helper) {
    bf16x8 hdB0 = *(const bf16x8*)(HIDb + sHid0);
    bf16x8 hdB1 = *(const bf16x8*)(HIDb + sHid1);
    bf16x8 hdB2 = *(const bf16x8*)(HIDb + sHid2);
    bf16x8 hdB3 = *(const bf16x8*)(HIDb + sHid3);
    f32x4 x0 = MFMA(aW2_0, hdB0, b2w),  x1 = MFMA(aW2_1, hdB1, zero4);
    f32x4 x2 = MFMA(aW2_2, hdB2, zero4), x3 = MFMA(aW2_3, hdB3, zero4);
    *(short4v*)(XGb + sW) = cvt4((x0 + x1) + (x2 + x3));
    // advance prefetch: regs <- x_1 (consumed in window B of iter 0)
    xp += 64;
    xa = *(const float4*)(xp);      xb = *(const float4*)(xp + 4);
    xc = *(const float4*)(xp + 32); xd = *(const float4*)(xp + 36);
  }
  barrier_lds();

  // =======================================================================
  // main scan
  // =======================================================================
  for (int t = 0; t < T_STEPS; ++t) {
    if (helper) {
      // ============== window A: GI_t ==============
      bf16x8 xgB0 = *(const bf16x8*)(XGb + sR0);
      bf16x8 xgB1 = *(const bf16x8*)(XGb + sR1);
      f32x4 gr0 = MFMA(aIR0, xgB0, bsr),  gr1 = MFMA(aIR1, xgB1, zero4);
      f32x4 gz0 = MFMA(aIZ0, xgB0, bsz),  gz1 = MFMA(aIZ1, xgB1, zero4);
      f32x4 gn0 = MFMA(aIN0, xgB0, bin_), gn1 = MFMA(aIN1, xgB1, zero4);
      *(f32x4*)(GIb + 0 * 4096 + giW) = gr0 + gr1;
      *(f32x4*)(GIb + 1 * 4096 + giW) = gz0 + gz1;
      *(f32x4*)(GIb + 2 * 4096 + giW) = gn0 + gn1;
      barrier_lds();
      // ============== window B: hid_{t+1} ==============
      if (t + 1 < T_STEPS) {
        bf16x8 xB0, xB1;
        xB0[0] = f2bf(xa.x); xB0[1] = f2bf(xa.y); xB0[2] = f2bf(xa.z); xB0[3] = f2bf(xa.w);
        xB0[4] = f2bf(xb.x); xB0[5] = f2bf(xb.y); xB0[6] = f2bf(xb.z); xB0[7] = f2bf(xb.w);
        xB1[0] = f2bf(xc.x); xB1[1] = f2bf(xc.y); xB1[2] = f2bf(xc.z); xB1[3] = f2bf(xc.w);
        xB1[4] = f2bf(xd.x); xB1[5] = f2bf(xd.y); xB1[6] = f2bf(xd.z); xB1[7] = f2bf(xd.w);
        if (t + 2 < T_STEPS) {  // prefetch x_{t+2}; stays in flight across lite barriers
          xp += 64;
          xa = *(const float4*)(xp);      xb = *(const float4*)(xp + 4);
          xc = *(const float4*)(xp + 32); xd = *(const float4*)(xp + 36);
        }
        f32x4 hid0 = MFMA(aW1_00, xB0, b1a), hid0b = MFMA(aW1_01, xB1, zero4);
        f32x4 hid1 = MFMA(aW1_10, xB0, b1b), hid1b = MFMA(aW1_11, xB1, zero4);
        hid0 += hid0b; hid1 += hid1b;
#pragma unroll
        for (int j = 0; j < 4; ++j) { hid0[j] = fmaxf(hid0[j], 0.f); hid1[j] = fmaxf(hid1[j], 0.f); }
        *(short4v*)(HIDb + sHidW0) = cvt4(hid0);
        *(short4v*)(HIDb + sHidW1) = cvt4(hid1);
      }
      barrier_lds();
      // ============== window C: xg_{t+1} + head t-1 ==============
      // (h_{t-1} lives in the READ buffer; crit writes h_t to the WRITE
      //  buffer in this same window -> no race, thanks to double-buffering.)
      if (t + 1 < T_STEPS) {
        bf16x8 hdB0 = *(const bf16x8*)(HIDb + sHid0);
        bf16x8 hdB1 = *(const bf16x8*)(HIDb + sHid1);
        bf16x8 hdB2 = *(const bf16x8*)(HIDb + sHid2);
        bf16x8 hdB3 = *(const bf16x8*)(HIDb + sHid3);
        f32x4 x0 = MFMA(aW2_0, hdB0, b2w),   x1 = MFMA(aW2_1, hdB1, zero4);
        f32x4 x2 = MFMA(aW2_2, hdB2, zero4), x3 = MFMA(aW2_3, hdB3, zero4);
        *(short4v*)(XGb + sW) = cvt4((x0 + x1) + (x2 + x3));
      }
      if (hw < 2 && t > 0) {
        bf16x8 hB0h = *(const bf16x8*)(HhiR + sR0);
        bf16x8 hB1h = *(const bf16x8*)(HhiR + sR1);
        bf16x8 hB0l = *(const bf16x8*)(HloR + sR0);
        bf16x8 hB1l = *(const bf16x8*)(HloR + sR1);
        f32x4 a5 = MFMA(aWr0, hB0h, brw),   a5b = MFMA(aWr1, hB1h, zero4);
        f32x4 a5l = MFMA(aWr0, hB0l, zero4), a5lb = MFMA(aWr1, hB1l, zero4);
        a5 = (a5 + a5b) + (a5l + a5lb);
        if (hw == 0 || g < 2) { outp[0] = a5[0]; outp[1] = a5[1]; outp[2] = a5[2]; outp[3] = a5[3]; }
        outp += 24;
      }
      barrier_lds();
    } else {
      __builtin_amdgcn_s_setprio(1);
      // ============== P0 (window A): r,z from h ==============
      bf16x8 hB0h = *(const bf16x8*)(HhiR + sR0);
      bf16x8 hB1h = *(const bf16x8*)(HhiR + sR1);
      bf16x8 hB0l = *(const bf16x8*)(HloR + sR0);
      bf16x8 hB1l = *(const bf16x8*)(HloR + sR1);
      // r first (its sigmoid gates the rh write); z issued after, sigmoid deferred
      f32x4 r00 = MFMA(aR0, hB0h, zero4), r10 = MFMA(aR1, hB1h, zero4);
      f32x4 r01 = MFMA(aR0, hB0l, zero4), r11 = MFMA(aR1, hB1l, zero4);
      f32x4 rr = sigm4((r00 + r10) + (r01 + r11));
      split_store(RHhi + sW, RHlo + sW, rr * hreg);
      f32x4 z00 = MFMA(aZ0, hB0h, zero4), z10 = MFMA(aZ1, hB1h, zero4);
      f32x4 z01 = MFMA(aZ0, hB0l, zero4), z11 = MFMA(aZ1, hB1l, zero4);
      f32x4 zz = sigm4((z00 + z10) + (z01 + z11));  // overlaps barrier wait
      barrier_lds();
      // ============== P1 (window B): u; ODE Euler; GI preload ==============
      bf16x8 rhB0h = *(const bf16x8*)(RHhi + sR0);
      bf16x8 rhB1h = *(const bf16x8*)(RHhi + sR1);
      bf16x8 rhB0l = *(const bf16x8*)(RHlo + sR0);
      bf16x8 rhB1l = *(const bf16x8*)(RHlo + sR1);
      // GI_t stable since end of window A: hoist reads here (consumed in C)
      f32x4 gir = *(const f32x4*)(GIb + 0 * 4096 + giR);
      f32x4 giz = *(const f32x4*)(GIb + 1 * 4096 + giR);
      f32x4 gin = *(const f32x4*)(GIb + 2 * 4096 + giR);
      f32x4 u00 = MFMA(aU0, rhB0h, zero4), u10 = MFMA(aU1, rhB1h, zero4);
      f32x4 u01 = MFMA(aU0, rhB0l, zero4), u11 = MFMA(aU1, rhB1l, zero4);
      f32x4 uu = tanh4((u00 + u10) + (u01 + u11));
      f32x4 hp = uu - zz * (uu - hreg);  // ODE Euler (DT=1): h + (1-z)(u-h)
      split_store(H2hi + sW, H2lo + sW, hp);
      barrier_lds();
      // ============== P2 (window C): GRU gates; h_new ==============
      bf16x8 h2B0h = *(const bf16x8*)(H2hi + sR0);
      bf16x8 h2B1h = *(const bf16x8*)(H2hi + sR1);
      bf16x8 h2B0l = *(const bf16x8*)(H2lo + sR0);
      bf16x8 h2B1l = *(const bf16x8*)(H2lo + sR1);
      // issue order = consumption order: hr (r2), hn (nn), hz (z2)
      f32x4 hr00 = MFMA(aHR0, h2B0h, zero4), hr10 = MFMA(aHR1, h2B1h, zero4);
      f32x4 hr01 = MFMA(aHR0, h2B0l, zero4), hr11 = MFMA(aHR1, h2B1l, zero4);
      f32x4 hn00 = MFMA(aHN0, h2B0h, bhn),   hn10 = MFMA(aHN1, h2B1h, zero4);
      f32x4 hn01 = MFMA(aHN0, h2B0l, zero4), hn11 = MFMA(aHN1, h2B1l, zero4);
      f32x4 hz00 = MFMA(aHZ0, h2B0h, zero4), hz10 = MFMA(aHZ1, h2B1h, zero4);
      f32x4 hz01 = MFMA(aHZ0, h2B0l, zero4), hz11 = MFMA(aHZ1, h2B1l, zero4);
      f32x4 r2 = sigm4(gir + (hr00 + hr10) + (hr01 + hr11));
      f32x4 nn = tanh4(gin + r2 * ((hn00 + hn10) + (hn01 + hn11)));
      f32x4 z2 = sigm4(giz + (hz00 + hz10) + (hz01 + hz11));
      hreg = nn + z2 * (hp - nn);  // h_new = (1-z2)*nn + z2*hp
      split_store(HhiW + sW, HloW + sW, hreg);
      __builtin_amdgcn_s_setprio(0);
      barrier_lds();
    }
    // swap h double-buffers (all waves)
    char* t0 = HhiR; HhiR = HhiW; HhiW = t0;
    char* t1 = HloR; HloR = HloW; HloW = t1;
  }

  // epilogue: output head for t = T-1 (read buffer now holds h_{T-1})
  if (helper && hw < 2) {
    bf16x8 hB0h = *(const bf16x8*)(HhiR + sR0);
    bf16x8 hB1h = *(const bf16x8*)(HhiR + sR1);
    bf16x8 hB0l = *(const bf16x8*)(HloR + sR0);
    bf16x8 hB1l = *(const bf16x8*)(HloR + sR1);
    f32x4 a5 = MFMA(aWr0, hB0h, brw),   a5b = MFMA(aWr1, hB1h, zero4);
    f32x4 a5l = MFMA(aWr0, hB0l, zero4), a5lb = MFMA(aWr1, hB1l, zero4);
    a5 = (a5 + a5b) + (a5l + a5lb);
    if (hw == 0 || g < 2) { outp[0] = a5[0]; outp[1] = a5[1]; outp[2] = a5[2]; outp[3] = a5[3]; }
  }
}

extern "C" void kernel_launch(void* const* d_in, const int* in_sizes, int n_in,
                              void* d_out, int out_size, void* d_ws, size_t ws_size,
                              hipStream_t stream) {
  (void)in_sizes; (void)n_in; (void)d_ws; (void)ws_size; (void)out_size;
  const float* H   = (const float*)d_in[0];
  // d_in[1] = times (unused: delta_t == 1 -> exactly one Euler step per observation)
  const float* W1  = (const float*)d_in[2];
  const float* b1  = (const float*)d_in[3];
  const float* W2  = (const float*)d_in[4];
  const float* b2  = (const float*)d_in[5];
  const float* Whr = (const float*)d_in[6];
  const float* Whz = (const float*)d_in[7];
  const float* Whh = (const float*)d_in[8];
  const float* wih = (const float*)d_in[9];
  const float* whh = (const float*)d_in[10];
  const float* bih = (const float*)d_in[11];
  const float* bhh = (const float*)d_in[12];
  const float* Wr  = (const float*)d_in[13];
  const float* br  = (const float*)d_in[14];
  float* out = (float*)d_out;

  odegru<<<dim3(2048 / 16), dim3(512), 0, stream>>>(
      H, W1, b1, W2, b2, Whr, Whz, Whh, wih, whh, bih, bhh, Wr, br, out);
}

// Round 11
// 308.775 us; speedup vs baseline: 1.1946x; 1.0815x over previous
//
#include <hip/hip_runtime.h>
#include <hip/hip_bf16.h>

// RecoveryODENetwork: fused x_model + GRU-ODE scan + output head, single kernel.
// B=2048, T=256, I=64, XH=128, G=Hd=64, O=24.
// Transposed matmuls Dt = W * h^T with MFMA 16x16x32 bf16.
//   A-frag (weights, const): lane holds A[row=l&15][k=8*(l>>4)+e]
//   B-frag (activations):    lane holds B[k=8*(l>>4)+e][col=l&15]   (col = batch)
//   D:                       lane holds D[row=4*(l>>4)+j][col=l&15] (m89-verified)
// Structure (R8 base = 313 us): 128 blocks x 512 thr. Waves 0-3 critical
// (recurrence), waves 4-7 helper. 3 windows/step (minimal barrier count):
//   A: helper GI_t            | crit P0 (r,z) + HEAD t-1 on waves 0-1 (R11)
//   B: helper hid_{t+1}       | crit P1 (u; ODE Euler)   [GI reads hoisted]
//   C: helper xg_{t+1}        | crit P2 (GRU gates; h_new)
// R7: k-frag accumulator split (MFMA chain 2->1), GI hoist, full-loop setprio.
// R8: perm-packed trunc splits, clamp-free tanh, fma-form updates.
// R11 (single isolated change vs R8): output head moved helper-A -> crit-P0
//   waves 0-1, REUSING the h B-fragments crit already loaded for r/z. Removes
//   4 ds_read_b128/step + helper-A's long pole; head MFMAs issue in the
//   r-MFMA dep-latency shadow; stores are fire-and-forget (no vmcnt drain).
// Recurrent operands (h, r*h, h') in LDS as bf16 hi+lo splits (exactness).
// Lite barriers (lgkmcnt only) keep x-prefetch global loads in flight.

#define T_STEPS 256

typedef short bf16x8 __attribute__((ext_vector_type(8)));
typedef short short4v __attribute__((ext_vector_type(4)));
typedef float f32x4 __attribute__((ext_vector_type(4)));

#define MFMA(a, b, c) __builtin_amdgcn_mfma_f32_16x16x32_bf16((a), (b), (c), 0, 0, 0)

// LDS-only barrier: orders ds ops across the block WITHOUT draining vmcnt.
__device__ __forceinline__ void barrier_lds() {
  asm volatile("s_waitcnt lgkmcnt(0)\n\ts_barrier" ::: "memory");
}

__device__ __forceinline__ short f2bf(float f) {
  __hip_bfloat16 b = __float2bfloat16(f);
  return __builtin_bit_cast(short, b);
}

__device__ __forceinline__ f32x4 sigm4(f32x4 x) {
  f32x4 r;
#pragma unroll
  for (int j = 0; j < 4; ++j) {
    float e = __builtin_amdgcn_exp2f(-1.442695041f * x[j]);
    r[j] = __builtin_amdgcn_rcpf(1.f + e);
  }
  return r;
}
// tanh(x) = 1 - 2/(exp2(2x*log2e)+1); inf/0 saturate correctly -> no clamp.
__device__ __forceinline__ f32x4 tanh4(f32x4 x) {
  f32x4 r;
#pragma unroll
  for (int j = 0; j < 4; ++j) {
    float e = __builtin_amdgcn_exp2f(2.885390082f * x[j]);
    r[j] = 1.f - 2.f * __builtin_amdgcn_rcpf(1.f + e);
  }
  return r;
}
__device__ __forceinline__ short4v cvt4(f32x4 v) {
  short4v p;
#pragma unroll
  for (int j = 0; j < 4; ++j) p[j] = f2bf(v[j]);
  return p;
}
// hi = trunc(v), lo = trunc(v - hi). Combined error ~2^-17 rel.
// Packing via v_perm_b32: 4 and + 4 sub + 4 perm = 12 VALU ops.
__device__ __forceinline__ void split_store(char* phi, char* plo, f32x4 v) {
  unsigned u0 = __builtin_bit_cast(unsigned, v[0]);
  unsigned u1 = __builtin_bit_cast(unsigned, v[1]);
  unsigned u2 = __builtin_bit_cast(unsigned, v[2]);
  unsigned u3 = __builtin_bit_cast(unsigned, v[3]);
  float l0 = v[0] - __builtin_bit_cast(float, u0 & 0xFFFF0000u);
  float l1 = v[1] - __builtin_bit_cast(float, u1 & 0xFFFF0000u);
  float l2 = v[2] - __builtin_bit_cast(float, u2 & 0xFFFF0000u);
  float l3 = v[3] - __builtin_bit_cast(float, u3 & 0xFFFF0000u);
  uint2 hi, lo;
  hi.x = __builtin_amdgcn_perm(u1, u0, 0x07060302u);  // [bf(v0), bf(v1)]
  hi.y = __builtin_amdgcn_perm(u3, u2, 0x07060302u);
  lo.x = __builtin_amdgcn_perm(__builtin_bit_cast(unsigned, l1),
                               __builtin_bit_cast(unsigned, l0), 0x07060302u);
  lo.y = __builtin_amdgcn_perm(__builtin_bit_cast(unsigned, l3),
                               __builtin_bit_cast(unsigned, l2), 0x07060302u);
  *(uint2*)phi = hi;
  *(uint2*)plo = lo;
}
__device__ __forceinline__ bf16x8 wfrag(const float* __restrict__ W, int stride, int row, int c0) {
  const float* p = W + (size_t)row * stride + c0;
  float4 a = *(const float4*)p;
  float4 b = *(const float4*)(p + 4);
  bf16x8 r;
  r[0] = f2bf(a.x); r[1] = f2bf(a.y); r[2] = f2bf(a.z); r[3] = f2bf(a.w);
  r[4] = f2bf(b.x); r[5] = f2bf(b.y); r[6] = f2bf(b.z); r[7] = f2bf(b.w);
  return r;
}

// XOR swizzle (G4): kills 16-way bank conflict of stride-128B/256B column reads
__device__ __forceinline__ int swz64(int row, int off) { return row * 128 + (off ^ ((row & 7) << 4)); }
__device__ __forceinline__ int swzH(int row, int off)  { return row * 256 + (off ^ ((row & 7) << 4)); }

__global__ __launch_bounds__(512, 1) void odegru(
    const float* __restrict__ H,
    const float* __restrict__ W1, const float* __restrict__ b1,
    const float* __restrict__ W2, const float* __restrict__ b2,
    const float* __restrict__ Wor, const float* __restrict__ Woz, const float* __restrict__ Woh,
    const float* __restrict__ wih, const float* __restrict__ whhg,
    const float* __restrict__ bih, const float* __restrict__ bhh,
    const float* __restrict__ Wr, const float* __restrict__ br,
    float* __restrict__ out) {
  const int tid = threadIdx.x;
  const int w = tid >> 6;          // wave 0..7
  const int l = tid & 63;
  const int col = l & 15;          // batch column within tile
  const int g = l >> 4;            // lane group
  const int b0 = blockIdx.x << 4;
  const bool helper = (w >= 4);
  const int hw = w - 4;            // helper wave index 0..3
  const f32x4 zero4 = {0.f, 0.f, 0.f, 0.f};

  __shared__ __align__(16) char sm[30720];
  char* HIDb = sm;            // [16 cols][256B] bf16 hid (x_model stage1), swizzled
  char* XGb  = sm + 4096;     // [16 cols][128B] bf16 xg, swizzled
  char* Hhi  = sm + 6144;     // h state hi
  char* Hlo  = sm + 8192;     // h state lo
  char* RHhi = sm + 10240;    // r*h hi
  char* RHlo = sm + 12288;    // r*h lo
  char* H2hi = sm + 14336;    // h' hi
  char* H2lo = sm + 16384;    // h' lo
  char* GIb  = sm + 18432;    // [gate3][wave4][lane64] float4 = 12288B

  // zero h state (hi+lo): 4096B, 512 threads x 8B
  ((long long*)Hhi)[tid] = 0;

  // ---- common LDS offsets ----
  const int row4 = 16 * (helper ? hw : w) + 4 * g;  // D-row base of this wave's tile
  const int r16 = 16 * (helper ? hw : w) + col;     // A-frag row base
  const int sR0 = swz64(col, 16 * g);
  const int sR1 = swz64(col, 64 + 16 * g);
  const int sW  = swz64(col, row4 * 2);

  // =======================================================================
  // per-role setup
  // =======================================================================
  bf16x8 aR0, aR1, aZ0, aZ1, aU0, aU1, aHR0, aHR1, aHZ0, aHZ1, aHN0, aHN1;
  bf16x8 aWr0, aWr1;               // head weights: crit waves 0-1 (R11)
  f32x4 bhn, brw;
  bf16x8 aW1_00, aW1_01, aW1_10, aW1_11, aW2_0, aW2_1, aW2_2, aW2_3;
  bf16x8 aIR0, aIR1, aIZ0, aIZ1, aIN0, aIN1;
  f32x4 bsr, bsz, bin_, b1a, b1b, b2w;
  const float* xp = nullptr;
  float4 xa, xb, xc, xd;
  float* outp = nullptr;
  int sHid0, sHid1, sHid2, sHid3, sHidW0, sHidW1, giW;
  const int giR = (w * 64 + l) * 16;  // identity mapping to helper hw==w, same lane

  if (!helper) {
    aR0 = wfrag(Wor, 64, r16, 8 * g);          aR1 = wfrag(Wor, 64, r16, 32 + 8 * g);
    aZ0 = wfrag(Woz, 64, r16, 8 * g);          aZ1 = wfrag(Woz, 64, r16, 32 + 8 * g);
    aU0 = wfrag(Woh, 64, r16, 8 * g);          aU1 = wfrag(Woh, 64, r16, 32 + 8 * g);
    aHR0 = wfrag(whhg, 64, r16, 8 * g);        aHR1 = wfrag(whhg, 64, r16, 32 + 8 * g);
    aHZ0 = wfrag(whhg, 64, 64 + r16, 8 * g);   aHZ1 = wfrag(whhg, 64, 64 + r16, 32 + 8 * g);
    aHN0 = wfrag(whhg, 64, 128 + r16, 8 * g);  aHN1 = wfrag(whhg, 64, 128 + r16, 32 + 8 * g);
#pragma unroll
    for (int j = 0; j < 4; ++j) bhn[j] = bhh[128 + row4 + j];
    // head (waves 0-1 use; loads clamped + uniform for all crit waves)
    const int wr_row = r16 > 23 ? 23 : r16;    // Wr has 24 rows; clamp (unused rows)
    aWr0 = wfrag(Wr, 64, wr_row, 8 * g);       aWr1 = wfrag(Wr, 64, wr_row, 32 + 8 * g);
#pragma unroll
    for (int j = 0; j < 4; ++j) {
      int o = row4 + j;
      brw[j] = br[o > 23 ? 23 : o];
    }
    outp = out + ((size_t)(b0 + col) * T_STEPS) * 24 + row4;
  } else {
    aW1_00 = wfrag(W1, 64, r16, 8 * g);        aW1_01 = wfrag(W1, 64, r16, 32 + 8 * g);
    aW1_10 = wfrag(W1, 64, 64 + r16, 8 * g);   aW1_11 = wfrag(W1, 64, 64 + r16, 32 + 8 * g);
    aW2_0 = wfrag(W2, 128, r16, 8 * g);        aW2_1 = wfrag(W2, 128, r16, 32 + 8 * g);
    aW2_2 = wfrag(W2, 128, r16, 64 + 8 * g);   aW2_3 = wfrag(W2, 128, r16, 96 + 8 * g);
    aIR0 = wfrag(wih, 64, r16, 8 * g);         aIR1 = wfrag(wih, 64, r16, 32 + 8 * g);
    aIZ0 = wfrag(wih, 64, 64 + r16, 8 * g);    aIZ1 = wfrag(wih, 64, 64 + r16, 32 + 8 * g);
    aIN0 = wfrag(wih, 64, 128 + r16, 8 * g);   aIN1 = wfrag(wih, 64, 128 + r16, 32 + 8 * g);
#pragma unroll
    for (int j = 0; j < 4; ++j) {
      bsr[j] = bih[row4 + j] + bhh[row4 + j];
      bsz[j] = bih[64 + row4 + j] + bhh[64 + row4 + j];
      bin_[j] = bih[128 + row4 + j];
      b1a[j] = b1[row4 + j];
      b1b[j] = b1[64 + row4 + j];
      b2w[j] = b2[row4 + j];
    }
    sHid0 = swzH(col, 16 * g);
    sHid1 = swzH(col, 64 + 16 * g);
    sHid2 = swzH(col, 128 + 16 * g);
    sHid3 = swzH(col, 192 + 16 * g);
    sHidW0 = swzH(col, row4 * 2);
    sHidW1 = swzH(col, (64 + row4) * 2);
    giW = (hw * 64 + l) * 16;
    xp = H + ((size_t)(b0 + col) * T_STEPS) * 64 + 8 * g;
    xa = *(const float4*)(xp);      xb = *(const float4*)(xp + 4);
    xc = *(const float4*)(xp + 32); xd = *(const float4*)(xp + 36);
  }

  f32x4 hreg = {0.f, 0.f, 0.f, 0.f};  // critical: h^T[row4+j][col] in fp32

  // =======================================================================
  // prologue: helpers compute hid_0, xg_0 so GI_0 is ready in loop iter 0
  // =======================================================================
  if (helper) {
    bf16x8 xB0, xB1;
    xB0[0] = f2bf(xa.x); xB0[1] = f2bf(xa.y); xB0[2] = f2bf(xa.z); xB0[3] = f2bf(xa.w);
    xB0[4] = f2bf(xb.x); xB0[5] = f2bf(xb.y); xB0[6] = f2bf(xb.z); xB0[7] = f2bf(xb.w);
    xB1[0] = f2bf(xc.x); xB1[1] = f2bf(xc.y); xB1[2] = f2bf(xc.z); xB1[3] = f2bf(xc.w);
    xB1[4] = f2bf(xd.x); xB1[5] = f2bf(xd.y); xB1[6] = f2bf(xd.z); xB1[7] = f2bf(xd.w);
    f32x4 hid0 = MFMA(aW1_00, xB0, b1a), hid0b = MFMA(aW1_01, xB1, zero4);
    f32x4 hid1 = MFMA(aW1_10, xB0, b1b), hid1b = MFMA(aW1_11, xB1, zero4);
    hid0 += hid0b; hid1 += hid1b;
#pragma unroll
    for (int j = 0; j < 4; ++j) { hid0[j] = fmaxf(hid0[j], 0.f); hid1[j] = fmaxf(hid1[j], 0.f); }
    *(short4v*)(HIDb + sHidW0) = cvt4(hid0);
    *(short4v*)(HIDb + sHidW1) = cvt4(hid1);
  }
  barrier_lds();
  if (helper) {
    bf16x8 hdB0 = *(const bf16x8*)(HIDb + sHid0);
    bf16x8 hdB1 = *(const bf16x8*)(HIDb + sHid1);
    bf16x8 hdB2 = *(const bf16x8*)(HIDb + sHid2);
    bf16x8 hdB3 = *(const bf16x8*)(HIDb + sHid3);
    f32x4 x0 = MFMA(aW2_0, hdB0, b2w),  x1 = MFMA(aW2_1, hdB1, zero4);
    f32x4 x2 = MFMA(aW2_2, hdB2, zero4), x3 = MFMA(aW2_3, hdB3, zero4);
    *(short4v*)(XGb + sW) = cvt4((x0 + x1) + (x2 + x3));
    // advance prefetch: regs <- x_1 (consumed in window B of iter 0)
    xp += 64;
    xa = *(const float4*)(xp);      xb = *(const float4*)(xp + 4);
    xc = *(const float4*)(xp + 32); xd = *(const float4*)(xp + 36);
  }
  barrier_lds();

  // =======================================================================
  // main scan
  // =======================================================================
  for (int t = 0; t < T_STEPS; ++t) {
    if (helper) {
      // ============== window A: GI_t ==============
      bf16x8 xgB0 = *(const bf16x8*)(XGb + sR0);
      bf16x8 xgB1 = *(const bf16x8*)(XGb + sR1);
      f32x4 gr0 = MFMA(aIR0, xgB0, bsr),  gr1 = MFMA(aIR1, xgB1, zero4);
      f32x4 gz0 = MFMA(aIZ0, xgB0, bsz),  gz1 = MFMA(aIZ1, xgB1, zero4);
      f32x4 gn0 = MFMA(aIN0, xgB0, bin_), gn1 = MFMA(aIN1, xgB1, zero4);
      *(f32x4*)(GIb + 0 * 4096 + giW) = gr0 + gr1;
      *(f32x4*)(GIb + 1 * 4096 + giW) = gz0 + gz1;
      *(f32x4*)(GIb + 2 * 4096 + giW) = gn0 + gn1;
      barrier_lds();
      // ============== window B: hid_{t+1} ==============
      if (t + 1 < T_STEPS) {
        bf16x8 xB0, xB1;
        xB0[0] = f2bf(xa.x); xB0[1] = f2bf(xa.y); xB0[2] = f2bf(xa.z); xB0[3] = f2bf(xa.w);
        xB0[4] = f2bf(xb.x); xB0[5] = f2bf(xb.y); xB0[6] = f2bf(xb.z); xB0[7] = f2bf(xb.w);
        xB1[0] = f2bf(xc.x); xB1[1] = f2bf(xc.y); xB1[2] = f2bf(xc.z); xB1[3] = f2bf(xc.w);
        xB1[4] = f2bf(xd.x); xB1[5] = f2bf(xd.y); xB1[6] = f2bf(xd.z); xB1[7] = f2bf(xd.w);
        if (t + 2 < T_STEPS) {  // prefetch x_{t+2}; stays in flight across lite barriers
          xp += 64;
          xa = *(const float4*)(xp);      xb = *(const float4*)(xp + 4);
          xc = *(const float4*)(xp + 32); xd = *(const float4*)(xp + 36);
        }
        f32x4 hid0 = MFMA(aW1_00, xB0, b1a), hid0b = MFMA(aW1_01, xB1, zero4);
        f32x4 hid1 = MFMA(aW1_10, xB0, b1b), hid1b = MFMA(aW1_11, xB1, zero4);
        hid0 += hid0b; hid1 += hid1b;
#pragma unroll
        for (int j = 0; j < 4; ++j) { hid0[j] = fmaxf(hid0[j], 0.f); hid1[j] = fmaxf(hid1[j], 0.f); }
        *(short4v*)(HIDb + sHidW0) = cvt4(hid0);
        *(short4v*)(HIDb + sHidW1) = cvt4(hid1);
      }
      barrier_lds();
      // ============== window C: xg_{t+1} ==============
      if (t + 1 < T_STEPS) {
        bf16x8 hdB0 = *(const bf16x8*)(HIDb + sHid0);
        bf16x8 hdB1 = *(const bf16x8*)(HIDb + sHid1);
        bf16x8 hdB2 = *(const bf16x8*)(HIDb + sHid2);
        bf16x8 hdB3 = *(const bf16x8*)(HIDb + sHid3);
        f32x4 x0 = MFMA(aW2_0, hdB0, b2w),   x1 = MFMA(aW2_1, hdB1, zero4);
        f32x4 x2 = MFMA(aW2_2, hdB2, zero4), x3 = MFMA(aW2_3, hdB3, zero4);
        *(short4v*)(XGb + sW) = cvt4((x0 + x1) + (x2 + x3));
      }
      barrier_lds();
    } else {
      __builtin_amdgcn_s_setprio(1);
      // ============== P0 (window A): r,z from h; head t-1 (waves 0-1) ==============
      bf16x8 hB0h = *(const bf16x8*)(Hhi + sR0);
      bf16x8 hB1h = *(const bf16x8*)(Hhi + sR1);
      bf16x8 hB0l = *(const bf16x8*)(Hlo + sR0);
      bf16x8 hB1l = *(const bf16x8*)(Hlo + sR1);
      // r first (its sigmoid gates the rh write); z after; head MFMAs fill the
      // r-dep-latency shadow (independent; reuse the SAME h fragments).
      f32x4 r00 = MFMA(aR0, hB0h, zero4), r10 = MFMA(aR1, hB1h, zero4);
      f32x4 r01 = MFMA(aR0, hB0l, zero4), r11 = MFMA(aR1, hB1l, zero4);
      f32x4 z00 = MFMA(aZ0, hB0h, zero4), z10 = MFMA(aZ1, hB1h, zero4);
      f32x4 z01 = MFMA(aZ0, hB0l, zero4), z11 = MFMA(aZ1, hB1l, zero4);
      f32x4 a5, a5b, a5l, a5lb;
      if (w < 2 && t > 0) {  // head for t-1 (h in LDS == h_{t-1})
        a5 = MFMA(aWr0, hB0h, brw);    a5b = MFMA(aWr1, hB1h, zero4);
        a5l = MFMA(aWr0, hB0l, zero4); a5lb = MFMA(aWr1, hB1l, zero4);
      }
      f32x4 rr = sigm4((r00 + r10) + (r01 + r11));
      split_store(RHhi + sW, RHlo + sW, rr * hreg);
      f32x4 zz = sigm4((z00 + z10) + (z01 + z11));  // overlaps barrier wait
      if (w < 2 && t > 0) {
        a5 = (a5 + a5b) + (a5l + a5lb);
        if (w == 0 || g < 2) { outp[0] = a5[0]; outp[1] = a5[1]; outp[2] = a5[2]; outp[3] = a5[3]; }
        outp += 24;  // store is fire-and-forget; lite barrier never drains vmcnt
      }
      barrier_lds();
      // ============== P1 (window B): u; ODE Euler; GI preload ==============
      bf16x8 rhB0h = *(const bf16x8*)(RHhi + sR0);
      bf16x8 rhB1h = *(const bf16x8*)(RHhi + sR1);
      bf16x8 rhB0l = *(const bf16x8*)(RHlo + sR0);
      bf16x8 rhB1l = *(const bf16x8*)(RHlo + sR1);
      // GI_t stable since end of window A: hoist reads here (consumed in C)
      f32x4 gir = *(const f32x4*)(GIb + 0 * 4096 + giR);
      f32x4 giz = *(const f32x4*)(GIb + 1 * 4096 + giR);
      f32x4 gin = *(const f32x4*)(GIb + 2 * 4096 + giR);
      f32x4 u00 = MFMA(aU0, rhB0h, zero4), u10 = MFMA(aU1, rhB1h, zero4);
      f32x4 u01 = MFMA(aU0, rhB0l, zero4), u11 = MFMA(aU1, rhB1l, zero4);
      f32x4 uu = tanh4((u00 + u10) + (u01 + u11));
      f32x4 hp = uu - zz * (uu - hreg);  // ODE Euler (DT=1): h + (1-z)(u-h)
      split_store(H2hi + sW, H2lo + sW, hp);
      barrier_lds();
      // ============== P2 (window C): GRU gates; h_new ==============
      bf16x8 h2B0h = *(const bf16x8*)(H2hi + sR0);
      bf16x8 h2B1h = *(const bf16x8*)(H2hi + sR1);
      bf16x8 h2B0l = *(const bf16x8*)(H2lo + sR0);
      bf16x8 h2B1l = *(const bf16x8*)(H2lo + sR1);
      // issue order = consumption order: hr (r2), hn (nn), hz (z2)
      f32x4 hr00 = MFMA(aHR0, h2B0h, zero4), hr10 = MFMA(aHR1, h2B1h, zero4);
      f32x4 hr01 = MFMA(aHR0, h2B0l, zero4), hr11 = MFMA(aHR1, h2B1l, zero4);
      f32x4 hn00 = MFMA(aHN0, h2B0h, bhn),   hn10 = MFMA(aHN1, h2B1h, zero4);
      f32x4 hn01 = MFMA(aHN0, h2B0l, zero4), hn11 = MFMA(aHN1, h2B1l, zero4);
      f32x4 hz00 = MFMA(aHZ0, h2B0h, zero4), hz10 = MFMA(aHZ1, h2B1h, zero4);
      f32x4 hz01 = MFMA(aHZ0, h2B0l, zero4), hz11 = MFMA(aHZ1, h2B1l, zero4);
      f32x4 r2 = sigm4(gir + (hr00 + hr10) + (hr01 + hr11));
      f32x4 nn = tanh4(gin + r2 * ((hn00 + hn10) + (hn01 + hn11)));
      f32x4 z2 = sigm4(giz + (hz00 + hz10) + (hz01 + hz11));
      hreg = nn + z2 * (hp - nn);  // h_new = (1-z2)*nn + z2*hp
      split_store(Hhi + sW, Hlo + sW, hreg);
      __builtin_amdgcn_s_setprio(0);
      barrier_lds();
    }
  }

  // epilogue: output head for t = T-1 (Hhi/Hlo hold h_{T-1}; crit waves 0-1)
  if (!helper && w < 2) {
    bf16x8 hB0h = *(const bf16x8*)(Hhi + sR0);
    bf16x8 hB1h = *(const bf16x8*)(Hhi + sR1);
    bf16x8 hB0l = *(const bf16x8*)(Hlo + sR0);
    bf16x8 hB1l = *(const bf16x8*)(Hlo + sR1);
    f32x4 a5 = MFMA(aWr0, hB0h, brw),   a5b = MFMA(aWr1, hB1h, zero4);
    f32x4 a5l = MFMA(aWr0, hB0l, zero4), a5lb = MFMA(aWr1, hB1l, zero4);
    a5 = (a5 + a5b) + (a5l + a5lb);
    if (w == 0 || g < 2) { outp[0] = a5[0]; outp[1] = a5[1]; outp[2] = a5[2]; outp[3] = a5[3]; }
  }
}

extern "C" void kernel_launch(void* const* d_in, const int* in_sizes, int n_in,
                              void* d_out, int out_size, void* d_ws, size_t ws_size,
                              hipStream_t stream) {
  (void)in_sizes; (void)n_in; (void)d_ws; (void)ws_size; (void)out_size;
  const float* H   = (const float*)d_in[0];
  // d_in[1] = times (unused: delta_t == 1 -> exactly one Euler step per observation)
  const float* W1  = (const float*)d_in[2];
  const float* b1  = (const float*)d_in[3];
  const float* W2  = (const float*)d_in[4];
  const float* b2  = (const float*)d_in[5];
  const float* Whr = (const float*)d_in[6];
  const float* Whz = (const float*)d_in[7];
  const float* Whh = (const float*)d_in[8];
  const float* wih = (const float*)d_in[9];
  const float* whh = (const float*)d_in[10];
  const float* bih = (const float*)d_in[11];
  const float* bhh = (const float*)d_in[12];
  const float* Wr  = (const float*)d_in[13];
  const float* br  = (const float*)d_in[14];
  float* out = (float*)d_out;

  odegru<<<dim3(2048 / 16), dim3(512), 0, stream>>>(
      H, W1, b1, W2, b2, Whr, Whz, Whh, wih, whh, bih, bhh, Wr, br, out);
}

// Round 12
// 304.150 us; speedup vs baseline: 1.2127x; 1.0152x over previous
//
#include <hip/hip_runtime.h>
#include <hip/hip_bf16.h>

// RecoveryODENetwork: fused x_model + GRU-ODE scan + output head, single kernel.
// B=2048, T=256, I=64, XH=128, G=Hd=64, O=24.
// Transposed matmuls Dt = W * h^T with MFMA 16x16x32 bf16.
//   A-frag (weights, const): lane holds A[row=l&15][k=8*(l>>4)+e]
//   B-frag (activations):    lane holds B[k=8*(l>>4)+e][col=l&15]   (col = batch)
//   D:                       lane holds D[row=4*(l>>4)+j][col=l&15] (m89-verified)
// Structure (R11 base = 309 us): 128 blocks x 512 thr. Waves 0-3 critical
// (recurrence), waves 4-7 helper. 3 windows/step (minimal barrier count):
//   A: helper idle            | crit P0 (r,z + GI + head t-1 on waves 0-1)
//   B: helper hid_{t+1}       | crit P1 (u; ODE Euler)
//   C: helper xg_{t+1}        | crit P2 (GRU gates; h_new)
// R7: k-frag accumulator split (MFMA chain 2->1), full-loop setprio.
// R8: perm-packed trunc splits, clamp-free tanh, fma-form updates.
// R11: head on crit-P0 waves 0-1, reusing P0's h B-fragments.
// R12 (single isolated change vs R11): GI_t moved helper-A -> crit-P0.
//   xg_t is stable in XGb from window C of t-1 through window C of t, so crit
//   reads the xg B-frags itself (2 ds_reads), issues the 6 GI MFMAs in the
//   r-sigmoid dep shadow, and carries gir/giz/gin in REGISTERS to P2.
//   Deletes the GIb LDS exchange (6 ops/step) + helper-A's long pole.
// Recurrent operands (h, r*h, h') in LDS as bf16 hi+lo splits (exactness).
// Lite barriers (lgkmcnt only) keep x-prefetch global loads in flight.

#define T_STEPS 256

typedef short bf16x8 __attribute__((ext_vector_type(8)));
typedef short short4v __attribute__((ext_vector_type(4)));
typedef float f32x4 __attribute__((ext_vector_type(4)));

#define MFMA(a, b, c) __builtin_amdgcn_mfma_f32_16x16x32_bf16((a), (b), (c), 0, 0, 0)

// LDS-only barrier: orders ds ops across the block WITHOUT draining vmcnt.
__device__ __forceinline__ void barrier_lds() {
  asm volatile("s_waitcnt lgkmcnt(0)\n\ts_barrier" ::: "memory");
}

__device__ __forceinline__ short f2bf(float f) {
  __hip_bfloat16 b = __float2bfloat16(f);
  return __builtin_bit_cast(short, b);
}

__device__ __forceinline__ f32x4 sigm4(f32x4 x) {
  f32x4 r;
#pragma unroll
  for (int j = 0; j < 4; ++j) {
    float e = __builtin_amdgcn_exp2f(-1.442695041f * x[j]);
    r[j] = __builtin_amdgcn_rcpf(1.f + e);
  }
  return r;
}
// tanh(x) = 1 - 2/(exp2(2x*log2e)+1); inf/0 saturate correctly -> no clamp.
__device__ __forceinline__ f32x4 tanh4(f32x4 x) {
  f32x4 r;
#pragma unroll
  for (int j = 0; j < 4; ++j) {
    float e = __builtin_amdgcn_exp2f(2.885390082f * x[j]);
    r[j] = 1.f - 2.f * __builtin_amdgcn_rcpf(1.f + e);
  }
  return r;
}
__device__ __forceinline__ short4v cvt4(f32x4 v) {
  short4v p;
#pragma unroll
  for (int j = 0; j < 4; ++j) p[j] = f2bf(v[j]);
  return p;
}
// hi = trunc(v), lo = trunc(v - hi). Combined error ~2^-17 rel.
// Packing via v_perm_b32: 4 and + 4 sub + 4 perm = 12 VALU ops.
__device__ __forceinline__ void split_store(char* phi, char* plo, f32x4 v) {
  unsigned u0 = __builtin_bit_cast(unsigned, v[0]);
  unsigned u1 = __builtin_bit_cast(unsigned, v[1]);
  unsigned u2 = __builtin_bit_cast(unsigned, v[2]);
  unsigned u3 = __builtin_bit_cast(unsigned, v[3]);
  float l0 = v[0] - __builtin_bit_cast(float, u0 & 0xFFFF0000u);
  float l1 = v[1] - __builtin_bit_cast(float, u1 & 0xFFFF0000u);
  float l2 = v[2] - __builtin_bit_cast(float, u2 & 0xFFFF0000u);
  float l3 = v[3] - __builtin_bit_cast(float, u3 & 0xFFFF0000u);
  uint2 hi, lo;
  hi.x = __builtin_amdgcn_perm(u1, u0, 0x07060302u);  // [bf(v0), bf(v1)]
  hi.y = __builtin_amdgcn_perm(u3, u2, 0x07060302u);
  lo.x = __builtin_amdgcn_perm(__builtin_bit_cast(unsigned, l1),
                               __builtin_bit_cast(unsigned, l0), 0x07060302u);
  lo.y = __builtin_amdgcn_perm(__builtin_bit_cast(unsigned, l3),
                               __builtin_bit_cast(unsigned, l2), 0x07060302u);
  *(uint2*)phi = hi;
  *(uint2*)plo = lo;
}
__device__ __forceinline__ bf16x8 wfrag(const float* __restrict__ W, int stride, int row, int c0) {
  const float* p = W + (size_t)row * stride + c0;
  float4 a = *(const float4*)p;
  float4 b = *(const float4*)(p + 4);
  bf16x8 r;
  r[0] = f2bf(a.x); r[1] = f2bf(a.y); r[2] = f2bf(a.z); r[3] = f2bf(a.w);
  r[4] = f2bf(b.x); r[5] = f2bf(b.y); r[6] = f2bf(b.z); r[7] = f2bf(b.w);
  return r;
}

// XOR swizzle (G4): kills 16-way bank conflict of stride-128B/256B column reads
__device__ __forceinline__ int swz64(int row, int off) { return row * 128 + (off ^ ((row & 7) << 4)); }
__device__ __forceinline__ int swzH(int row, int off)  { return row * 256 + (off ^ ((row & 7) << 4)); }

__global__ __launch_bounds__(512, 1) void odegru(
    const float* __restrict__ H,
    const float* __restrict__ W1, const float* __restrict__ b1,
    const float* __restrict__ W2, const float* __restrict__ b2,
    const float* __restrict__ Wor, const float* __restrict__ Woz, const float* __restrict__ Woh,
    const float* __restrict__ wih, const float* __restrict__ whhg,
    const float* __restrict__ bih, const float* __restrict__ bhh,
    const float* __restrict__ Wr, const float* __restrict__ br,
    float* __restrict__ out) {
  const int tid = threadIdx.x;
  const int w = tid >> 6;          // wave 0..7
  const int l = tid & 63;
  const int col = l & 15;          // batch column within tile
  const int g = l >> 4;            // lane group
  const int b0 = blockIdx.x << 4;
  const bool helper = (w >= 4);
  const int hw = w - 4;            // helper wave index 0..3
  const f32x4 zero4 = {0.f, 0.f, 0.f, 0.f};

  __shared__ __align__(16) char sm[18432];
  char* HIDb = sm;            // [16 cols][256B] bf16 hid (x_model stage1), swizzled
  char* XGb  = sm + 4096;     // [16 cols][128B] bf16 xg, swizzled
  char* Hhi  = sm + 6144;     // h state hi
  char* Hlo  = sm + 8192;     // h state lo
  char* RHhi = sm + 10240;    // r*h hi
  char* RHlo = sm + 12288;    // r*h lo
  char* H2hi = sm + 14336;    // h' hi
  char* H2lo = sm + 16384;    // h' lo

  // zero h state (hi+lo): 4096B, 512 threads x 8B
  ((long long*)Hhi)[tid] = 0;

  // ---- common LDS offsets ----
  const int row4 = 16 * (helper ? hw : w) + 4 * g;  // D-row base of this wave's tile
  const int r16 = 16 * (helper ? hw : w) + col;     // A-frag row base
  const int sR0 = swz64(col, 16 * g);
  const int sR1 = swz64(col, 64 + 16 * g);
  const int sW  = swz64(col, row4 * 2);

  // =======================================================================
  // per-role setup
  // =======================================================================
  bf16x8 aR0, aR1, aZ0, aZ1, aU0, aU1, aHR0, aHR1, aHZ0, aHZ1, aHN0, aHN1;
  bf16x8 aIR0, aIR1, aIZ0, aIZ1, aIN0, aIN1;   // GI weights: crit (R12)
  bf16x8 aWr0, aWr1;                           // head weights: crit waves 0-1 (R11)
  f32x4 bhn, brw, bsr, bsz, bin_;
  bf16x8 aW1_00, aW1_01, aW1_10, aW1_11, aW2_0, aW2_1, aW2_2, aW2_3;
  f32x4 b1a, b1b, b2w;
  const float* xp = nullptr;
  float4 xa, xb, xc, xd;
  float* outp = nullptr;
  int sHid0, sHid1, sHid2, sHid3, sHidW0, sHidW1;

  if (!helper) {
    aR0 = wfrag(Wor, 64, r16, 8 * g);          aR1 = wfrag(Wor, 64, r16, 32 + 8 * g);
    aZ0 = wfrag(Woz, 64, r16, 8 * g);          aZ1 = wfrag(Woz, 64, r16, 32 + 8 * g);
    aU0 = wfrag(Woh, 64, r16, 8 * g);          aU1 = wfrag(Woh, 64, r16, 32 + 8 * g);
    aHR0 = wfrag(whhg, 64, r16, 8 * g);        aHR1 = wfrag(whhg, 64, r16, 32 + 8 * g);
    aHZ0 = wfrag(whhg, 64, 64 + r16, 8 * g);   aHZ1 = wfrag(whhg, 64, 64 + r16, 32 + 8 * g);
    aHN0 = wfrag(whhg, 64, 128 + r16, 8 * g);  aHN1 = wfrag(whhg, 64, 128 + r16, 32 + 8 * g);
    aIR0 = wfrag(wih, 64, r16, 8 * g);         aIR1 = wfrag(wih, 64, r16, 32 + 8 * g);
    aIZ0 = wfrag(wih, 64, 64 + r16, 8 * g);    aIZ1 = wfrag(wih, 64, 64 + r16, 32 + 8 * g);
    aIN0 = wfrag(wih, 64, 128 + r16, 8 * g);   aIN1 = wfrag(wih, 64, 128 + r16, 32 + 8 * g);
#pragma unroll
    for (int j = 0; j < 4; ++j) {
      bhn[j] = bhh[128 + row4 + j];
      bsr[j] = bih[row4 + j] + bhh[row4 + j];
      bsz[j] = bih[64 + row4 + j] + bhh[64 + row4 + j];
      bin_[j] = bih[128 + row4 + j];
    }
    // head (waves 0-1 use; loads clamped + uniform for all crit waves)
    const int wr_row = r16 > 23 ? 23 : r16;    // Wr has 24 rows; clamp (unused rows)
    aWr0 = wfrag(Wr, 64, wr_row, 8 * g);       aWr1 = wfrag(Wr, 64, wr_row, 32 + 8 * g);
#pragma unroll
    for (int j = 0; j < 4; ++j) {
      int o = row4 + j;
      brw[j] = br[o > 23 ? 23 : o];
    }
    outp = out + ((size_t)(b0 + col) * T_STEPS) * 24 + row4;
  } else {
    aW1_00 = wfrag(W1, 64, r16, 8 * g);        aW1_01 = wfrag(W1, 64, r16, 32 + 8 * g);
    aW1_10 = wfrag(W1, 64, 64 + r16, 8 * g);   aW1_11 = wfrag(W1, 64, 64 + r16, 32 + 8 * g);
    aW2_0 = wfrag(W2, 128, r16, 8 * g);        aW2_1 = wfrag(W2, 128, r16, 32 + 8 * g);
    aW2_2 = wfrag(W2, 128, r16, 64 + 8 * g);   aW2_3 = wfrag(W2, 128, r16, 96 + 8 * g);
#pragma unroll
    for (int j = 0; j < 4; ++j) {
      b1a[j] = b1[row4 + j];
      b1b[j] = b1[64 + row4 + j];
      b2w[j] = b2[row4 + j];
    }
    sHid0 = swzH(col, 16 * g);
    sHid1 = swzH(col, 64 + 16 * g);
    sHid2 = swzH(col, 128 + 16 * g);
    sHid3 = swzH(col, 192 + 16 * g);
    sHidW0 = swzH(col, row4 * 2);
    sHidW1 = swzH(col, (64 + row4) * 2);
    xp = H + ((size_t)(b0 + col) * T_STEPS) * 64 + 8 * g;
    xa = *(const float4*)(xp);      xb = *(const float4*)(xp + 4);
    xc = *(const float4*)(xp + 32); xd = *(const float4*)(xp + 36);
  }

  f32x4 hreg = {0.f, 0.f, 0.f, 0.f};  // critical: h^T[row4+j][col] in fp32

  // =======================================================================
  // prologue: helpers compute hid_0, xg_0 so xg_0 is in XGb for loop iter 0
  // =======================================================================
  if (helper) {
    bf16x8 xB0, xB1;
    xB0[0] = f2bf(xa.x); xB0[1] = f2bf(xa.y); xB0[2] = f2bf(xa.z); xB0[3] = f2bf(xa.w);
    xB0[4] = f2bf(xb.x); xB0[5] = f2bf(xb.y); xB0[6] = f2bf(xb.z); xB0[7] = f2bf(xb.w);
    xB1[0] = f2bf(xc.x); xB1[1] = f2bf(xc.y); xB1[2] = f2bf(xc.z); xB1[3] = f2bf(xc.w);
    xB1[4] = f2bf(xd.x); xB1[5] = f2bf(xd.y); xB1[6] = f2bf(xd.z); xB1[7] = f2bf(xd.w);
    f32x4 hid0 = MFMA(aW1_00, xB0, b1a), hid0b = MFMA(aW1_01, xB1, zero4);
    f32x4 hid1 = MFMA(aW1_10, xB0, b1b), hid1b = MFMA(aW1_11, xB1, zero4);
    hid0 += hid0b; hid1 += hid1b;
#pragma unroll
    for (int j = 0; j < 4; ++j) { hid0[j] = fmaxf(hid0[j], 0.f); hid1[j] = fmaxf(hid1[j], 0.f); }
    *(short4v*)(HIDb + sHidW0) = cvt4(hid0);
    *(short4v*)(HIDb + sHidW1) = cvt4(hid1);
  }
  barrier_lds();
  if (helper) {
    bf16x8 hdB0 = *(const bf16x8*)(HIDb + sHid0);
    bf16x8 hdB1 = *(const bf16x8*)(HIDb + sHid1);
    bf16x8 hdB2 = *(const bf16x8*)(HIDb + sHid2);
    bf16x8 hdB3 = *(const bf16x8*)(HIDb + sHid3);
    f32x4 x0 = MFMA(aW2_0, hdB0, b2w),  x1 = MFMA(aW2_1, hdB1, zero4);
    f32x4 x2 = MFMA(aW2_2, hdB2, zero4), x3 = MFMA(aW2_3, hdB3, zero4);
    *(short4v*)(XGb + sW) = cvt4((x0 + x1) + (x2 + x3));
    // advance prefetch: regs <- x_1 (consumed in window B of iter 0)
    xp += 64;
    xa = *(const float4*)(xp);      xb = *(const float4*)(xp + 4);
    xc = *(const float4*)(xp + 32); xd = *(const float4*)(xp + 36);
  }
  barrier_lds();

  // =======================================================================
  // main scan
  // =======================================================================
  for (int t = 0; t < T_STEPS; ++t) {
    if (helper) {
      // ============== window A: idle (GI moved to crit, R12) ==============
      barrier_lds();
      // ============== window B: hid_{t+1} ==============
      if (t + 1 < T_STEPS) {
        bf16x8 xB0, xB1;
        xB0[0] = f2bf(xa.x); xB0[1] = f2bf(xa.y); xB0[2] = f2bf(xa.z); xB0[3] = f2bf(xa.w);
        xB0[4] = f2bf(xb.x); xB0[5] = f2bf(xb.y); xB0[6] = f2bf(xb.z); xB0[7] = f2bf(xb.w);
        xB1[0] = f2bf(xc.x); xB1[1] = f2bf(xc.y); xB1[2] = f2bf(xc.z); xB1[3] = f2bf(xc.w);
        xB1[4] = f2bf(xd.x); xB1[5] = f2bf(xd.y); xB1[6] = f2bf(xd.z); xB1[7] = f2bf(xd.w);
        if (t + 2 < T_STEPS) {  // prefetch x_{t+2}; stays in flight across lite barriers
          xp += 64;
          xa = *(const float4*)(xp);      xb = *(const float4*)(xp + 4);
          xc = *(const float4*)(xp + 32); xd = *(const float4*)(xp + 36);
        }
        f32x4 hid0 = MFMA(aW1_00, xB0, b1a), hid0b = MFMA(aW1_01, xB1, zero4);
        f32x4 hid1 = MFMA(aW1_10, xB0, b1b), hid1b = MFMA(aW1_11, xB1, zero4);
        hid0 += hid0b; hid1 += hid1b;
#pragma unroll
        for (int j = 0; j < 4; ++j) { hid0[j] = fmaxf(hid0[j], 0.f); hid1[j] = fmaxf(hid1[j], 0.f); }
        *(short4v*)(HIDb + sHidW0) = cvt4(hid0);
        *(short4v*)(HIDb + sHidW1) = cvt4(hid1);
      }
      barrier_lds();
      // ============== window C: xg_{t+1} ==============
      if (t + 1 < T_STEPS) {
        bf16x8 hdB0 = *(const bf16x8*)(HIDb + sHid0);
        bf16x8 hdB1 = *(const bf16x8*)(HIDb + sHid1);
        bf16x8 hdB2 = *(const bf16x8*)(HIDb + sHid2);
        bf16x8 hdB3 = *(const bf16x8*)(HIDb + sHid3);
        f32x4 x0 = MFMA(aW2_0, hdB0, b2w),   x1 = MFMA(aW2_1, hdB1, zero4);
        f32x4 x2 = MFMA(aW2_2, hdB2, zero4), x3 = MFMA(aW2_3, hdB3, zero4);
        *(short4v*)(XGb + sW) = cvt4((x0 + x1) + (x2 + x3));
      }
      barrier_lds();
    } else {
      __builtin_amdgcn_s_setprio(1);
      // ====== P0 (window A): r,z + GI_t + head t-1 (waves 0-1) ======
      bf16x8 hB0h = *(const bf16x8*)(Hhi + sR0);
      bf16x8 hB1h = *(const bf16x8*)(Hhi + sR1);
      bf16x8 hB0l = *(const bf16x8*)(Hlo + sR0);
      bf16x8 hB1l = *(const bf16x8*)(Hlo + sR1);
      // xg_t: stable in XGb from window C of t-1 through window C of t (R12)
      bf16x8 xgB0 = *(const bf16x8*)(XGb + sR0);
      bf16x8 xgB1 = *(const bf16x8*)(XGb + sR1);
      // r first (its sigmoid gates the rh write); z after; head + GI MFMAs
      // fill the r-dep-latency shadow (all independent of the r-chain).
      f32x4 r00 = MFMA(aR0, hB0h, zero4), r10 = MFMA(aR1, hB1h, zero4);
      f32x4 r01 = MFMA(aR0, hB0l, zero4), r11 = MFMA(aR1, hB1l, zero4);
      f32x4 z00 = MFMA(aZ0, hB0h, zero4), z10 = MFMA(aZ1, hB1h, zero4);
      f32x4 z01 = MFMA(aZ0, hB0l, zero4), z11 = MFMA(aZ1, hB1l, zero4);
      f32x4 a5, a5b, a5l, a5lb;
      if (w < 2 && t > 0) {  // head for t-1 (h in LDS == h_{t-1})
        a5 = MFMA(aWr0, hB0h, brw);    a5b = MFMA(aWr1, hB1h, zero4);
        a5l = MFMA(aWr0, hB0l, zero4); a5lb = MFMA(aWr1, hB1l, zero4);
      }
      f32x4 gr0 = MFMA(aIR0, xgB0, bsr),  gr1 = MFMA(aIR1, xgB1, zero4);
      f32x4 gz0 = MFMA(aIZ0, xgB0, bsz),  gz1 = MFMA(aIZ1, xgB1, zero4);
      f32x4 gn0 = MFMA(aIN0, xgB0, bin_), gn1 = MFMA(aIN1, xgB1, zero4);
      f32x4 rr = sigm4((r00 + r10) + (r01 + r11));
      split_store(RHhi + sW, RHlo + sW, rr * hreg);
      f32x4 zz = sigm4((z00 + z10) + (z01 + z11));  // overlaps barrier wait
      if (w < 2 && t > 0) {
        a5 = (a5 + a5b) + (a5l + a5lb);
        if (w == 0 || g < 2) { outp[0] = a5[0]; outp[1] = a5[1]; outp[2] = a5[2]; outp[3] = a5[3]; }
        outp += 24;  // store is fire-and-forget; lite barrier never drains vmcnt
      }
      f32x4 gir = gr0 + gr1, giz = gz0 + gz1, gin = gn0 + gn1;  // regs to P2
      barrier_lds();
      // ============== P1 (window B): u; ODE Euler ==============
      bf16x8 rhB0h = *(const bf16x8*)(RHhi + sR0);
      bf16x8 rhB1h = *(const bf16x8*)(RHhi + sR1);
      bf16x8 rhB0l = *(const bf16x8*)(RHlo + sR0);
      bf16x8 rhB1l = *(const bf16x8*)(RHlo + sR1);
      f32x4 u00 = MFMA(aU0, rhB0h, zero4), u10 = MFMA(aU1, rhB1h, zero4);
      f32x4 u01 = MFMA(aU0, rhB0l, zero4), u11 = MFMA(aU1, rhB1l, zero4);
      f32x4 uu = tanh4((u00 + u10) + (u01 + u11));
      f32x4 hp = uu - zz * (uu - hreg);  // ODE Euler (DT=1): h + (1-z)(u-h)
      split_store(H2hi + sW, H2lo + sW, hp);
      barrier_lds();
      // ============== P2 (window C): GRU gates; h_new ==============
      bf16x8 h2B0h = *(const bf16x8*)(H2hi + sR0);
      bf16x8 h2B1h = *(const bf16x8*)(H2hi + sR1);
      bf16x8 h2B0l = *(const bf16x8*)(H2lo + sR0);
      bf16x8 h2B1l = *(const bf16x8*)(H2lo + sR1);
      // issue order = consumption order: hr (r2), hn (nn), hz (z2)
      f32x4 hr00 = MFMA(aHR0, h2B0h, zero4), hr10 = MFMA(aHR1, h2B1h, zero4);
      f32x4 hr01 = MFMA(aHR0, h2B0l, zero4), hr11 = MFMA(aHR1, h2B1l, zero4);
      f32x4 hn00 = MFMA(aHN0, h2B0h, bhn),   hn10 = MFMA(aHN1, h2B1h, zero4);
      f32x4 hn01 = MFMA(aHN0, h2B0l, zero4), hn11 = MFMA(aHN1, h2B1l, zero4);
      f32x4 hz00 = MFMA(aHZ0, h2B0h, zero4), hz10 = MFMA(aHZ1, h2B1h, zero4);
      f32x4 hz01 = MFMA(aHZ0, h2B0l, zero4), hz11 = MFMA(aHZ1, h2B1l, zero4);
      f32x4 r2 = sigm4(gir + (hr00 + hr10) + (hr01 + hr11));
      f32x4 nn = tanh4(gin + r2 * ((hn00 + hn10) + (hn01 + hn11)));
      f32x4 z2 = sigm4(giz + (hz00 + hz10) + (hz01 + hz11));
      hreg = nn + z2 * (hp - nn);  // h_new = (1-z2)*nn + z2*hp
      split_store(Hhi + sW, Hlo + sW, hreg);
      __builtin_amdgcn_s_setprio(0);
      barrier_lds();
    }
  }

  // epilogue: output head for t = T-1 (Hhi/Hlo hold h_{T-1}; crit waves 0-1)
  if (!helper && w < 2) {
    bf16x8 hB0h = *(const bf16x8*)(Hhi + sR0);
    bf16x8 hB1h = *(const bf16x8*)(Hhi + sR1);
    bf16x8 hB0l = *(const bf16x8*)(Hlo + sR0);
    bf16x8 hB1l = *(const bf16x8*)(Hlo + sR1);
    f32x4 a5 = MFMA(aWr0, hB0h, brw),   a5b = MFMA(aWr1, hB1h, zero4);
    f32x4 a5l = MFMA(aWr0, hB0l, zero4), a5lb = MFMA(aWr1, hB1l, zero4);
    a5 = (a5 + a5b) + (a5l + a5lb);
    if (w == 0 || g < 2) { outp[0] = a5[0]; outp[1] = a5[1]; outp[2] = a5[2]; outp[3] = a5[3]; }
  }
}

extern "C" void kernel_launch(void* const* d_in, const int* in_sizes, int n_in,
                              void* d_out, int out_size, void* d_ws, size_t ws_size,
                              hipStream_t stream) {
  (void)in_sizes; (void)n_in; (void)d_ws; (void)ws_size; (void)out_size;
  const float* H   = (const float*)d_in[0];
  // d_in[1] = times (unused: delta_t == 1 -> exactly one Euler step per observation)
  const float* W1  = (const float*)d_in[2];
  const float* b1  = (const float*)d_in[3];
  const float* W2  = (const float*)d_in[4];
  const float* b2  = (const float*)d_in[5];
  const float* Whr = (const float*)d_in[6];
  const float* Whz = (const float*)d_in[7];
  const float* Whh = (const float*)d_in[8];
  const float* wih = (const float*)d_in[9];
  const float* whh = (const float*)d_in[10];
  const float* bih = (const float*)d_in[11];
  const float* bhh = (const float*)d_in[12];
  const float* Wr  = (const float*)d_in[13];
  const float* br  = (const float*)d_in[14];
  float* out = (float*)d_out;

  odegru<<<dim3(2048 / 16), dim3(512), 0, stream>>>(
      H, W1, b1, W2, b2, Whr, Whz, Whh, wih, whh, bih, bhh, Wr, br, out);
}